// Round 5
// baseline (93.677 us; speedup 1.0000x reference)
//
#include <hip/hip_runtime.h>
#include <math.h>

namespace {
constexpr int Bn = 8;
constexpr int Ln = 8192;
constexpr int Rn = 64;
constexpr int Hn = 512;
constexpr int LT = 128;
constexpr int NSEG = Ln / LT;            // 64 segments per batch
constexpr int NK1 = Bn * NSEG;           // 512 k1 blocks
constexpr int NHC = 4;                   // M h-chunks (128 h each)

// workspace float offsets
constexpr size_t PS        = 8352;       // per-k1-block partial stride
constexpr size_t OFF_G     = 0;                                   // 64x64
constexpr size_t OFF_W     = 4096;                                // 64
constexpr size_t OFF_BB    = 4160;                                // 1 (+pad)
constexpr size_t OFF_STATS = 4224;                                // NK1 * PS
constexpr size_t OFF_A1R   = OFF_STATS + (size_t)NK1 * PS;        // B*4096
constexpr size_t OFF_A2R   = OFF_A1R + (size_t)Bn * 4096;         // B*4096
constexpr size_t OFF_U1R   = OFF_A2R + (size_t)Bn * 4096;         // B*64
constexpr size_t OFF_U2R   = OFF_U1R + (size_t)Bn * 64;           // B*64
constexpr size_t OFF_SIG   = OFF_U2R + (size_t)Bn * 64;           // B*2 (pad 64)
constexpr size_t OFF_MP    = OFF_SIG + 64;                        // B*NHC*64*H (M h-partials)
constexpr size_t OFF_C1P   = OFF_MP + (size_t)Bn * NHC * 64 * Hn; // B*NHC*H
constexpr size_t OFF_TD    = OFF_C1P + (size_t)Bn * NHC * Hn;     // B*64*H
constexpr size_t OFF_P1    = OFF_TD + (size_t)Bn * 64 * Hn;       // B*H
constexpr size_t OFF_P2    = OFF_P1 + (size_t)Bn * Hn;            // B*H
constexpr size_t OFF_Q1    = OFF_P2 + (size_t)Bn * Hn;            // B*H
constexpr size_t OFF_GV    = OFF_Q1 + (size_t)Bn * Hn;            // B*H     (g = u2^T M)
}

// swizzled XT index: row-stride 128, col4 XOR'd with (r>>2)&7 -> all k1 LDS
// accesses are <=2-way bank aliased (free on CDNA4).
__device__ __forceinline__ int xtidx(int r, int l) {
  return r * 128 + ((((l >> 2) ^ ((r >> 2) & 7)) << 2) | (l & 3));
}

// ---------------------------------------------------------------------------
// kG: blocks 0..63: G[i][j] = Wk_i . Wk_j ; block 64: w = Wk*bk, bb = bk.bk
// grid 65 x 256
__global__ __launch_bounds__(256) void kG_pre(const float* __restrict__ Wk,
                                              const float* __restrict__ bk,
                                              float* __restrict__ ws) {
  const int t = threadIdx.x;
  const int blk = blockIdx.x;
  if (blk < 64) {
    const int j = t >> 2, kq = t & 3;
    const float4* a4 = (const float4*)(Wk + (size_t)blk * Hn) + kq * 32;
    const float4* b4 = (const float4*)(Wk + (size_t)j * Hn) + kq * 32;
    float s0 = 0.f, s1 = 0.f, s2 = 0.f, s3 = 0.f;
    #pragma unroll 8
    for (int h = 0; h < 32; ++h) {
      const float4 x = a4[h], y = b4[h];
      s0 += x.x * y.x; s1 += x.y * y.y; s2 += x.z * y.z; s3 += x.w * y.w;
    }
    float s = (s0 + s1) + (s2 + s3);
    s += __shfl_down(s, 2, 4);
    s += __shfl_down(s, 1, 4);
    if (kq == 0) ws[OFF_G + blk * 64 + j] = s;
    return;
  }
  const int i = t >> 2, kq = t & 3;
  const float4* a4 = (const float4*)(Wk + (size_t)i * Hn) + kq * 32;
  const float4* b4 = (const float4*)bk + kq * 32;
  float s0 = 0.f, s1 = 0.f, s2 = 0.f, s3 = 0.f;
  #pragma unroll 8
  for (int h = 0; h < 32; ++h) {
    const float4 x = a4[h], y = b4[h];
    s0 += x.x * y.x; s1 += x.y * y.y; s2 += x.z * y.z; s3 += x.w * y.w;
  }
  float s = (s0 + s1) + (s2 + s3);
  s += __shfl_down(s, 2, 4);
  s += __shfl_down(s, 1, 4);
  if (kq == 0) ws[OFF_W + i] = s;
  if (t < 4) {
    const float4* b4b = (const float4*)bk + t * 32;
    float q0 = 0.f, q1 = 0.f, q2 = 0.f, q3 = 0.f;
    #pragma unroll 8
    for (int h = 0; h < 32; ++h) {
      const float4 y = b4b[h];
      q0 += y.x * y.x; q1 += y.y * y.y; q2 += y.z * y.z; q3 += y.w * y.w;
    }
    float q = (q0 + q1) + (q2 + q3);
    q += __shfl_down(q, 2, 4);
    q += __shfl_down(q, 1, 4);
    if (t == 0) ws[OFF_BB] = q;
  }
}

// ---------------------------------------------------------------------------
// k1M: grid 1024. blk&1==0 -> k1 stats block (idx 0..511);
//                 blk&1==1 -> M/c1 partial block (idx 0..511).
// Interleaved so VALU-bound stats blocks co-schedule with memory-bound M blocks.
__global__ __launch_bounds__(256) void k1M(const float* __restrict__ hs,
                                           const float* __restrict__ Wk,
                                           const float* __restrict__ bk,
                                           const float* __restrict__ C,
                                           float* __restrict__ ws) {
  __shared__ __align__(16) float SH[13632];   // 54.5 KB overlay
  const int t = threadIdx.x;
  const int role = blockIdx.x & 1;
  const int idx = blockIdx.x >> 1;

  if (role == 1) {
    // ---- M / c1 partials: MP[b][hc] = Wk[:,chunk] @ C[chunk, dstrip] ----
    float* Wks = SH;               // [64][132]
    float* Cs  = SH + 8448;        // [128][36]
    float* bks = SH + 13056;       // [128]
    const int b = idx >> 6;
    const int rem = idx & 63;
    const int hc = rem >> 4;
    const int ds = rem & 15;
    const int h0 = hc * 128;
    const int d04 = ds * 8;

    const float4* Wk4 = (const float4*)Wk;
    const float4* C4b = (const float4*)(C + (size_t)b * Hn * Hn);
    #pragma unroll
    for (int p = 0; p < 8; ++p) {
      const int e = p * 256 + t;                // 2048 float4 (64 x 32)
      const int r = e >> 5, c4 = e & 31;
      *(float4*)&Wks[r * 132 + c4 * 4] = Wk4[(size_t)r * 128 + (h0 >> 2) + c4];
    }
    #pragma unroll
    for (int p = 0; p < 4; ++p) {
      const int e = p * 256 + t;                // 1024 float4 (128 x 8)
      const int r = e >> 3, c4 = e & 7;
      *(float4*)&Cs[r * 36 + c4 * 4] = C4b[(size_t)(h0 + r) * 128 + d04 + c4];
    }
    if (t < 32) *(float4*)&bks[t * 4] = *(const float4*)&bk[h0 + t * 4];
    __syncthreads();

    const int ig = t >> 3;                      // rows 2ig, 2ig+1
    const int tj4 = t & 7;
    float4 acc0 = make_float4(0.f, 0.f, 0.f, 0.f);
    float4 acc1 = make_float4(0.f, 0.f, 0.f, 0.f);
    float4 c1a  = make_float4(0.f, 0.f, 0.f, 0.f);
    #pragma unroll 8
    for (int hh = 0; hh < 128; ++hh) {
      const float4 cv = *(const float4*)&Cs[hh * 36 + tj4 * 4];
      const float w0 = Wks[(ig * 2) * 132 + hh];
      const float w1 = Wks[(ig * 2 + 1) * 132 + hh];
      acc0.x += w0 * cv.x; acc0.y += w0 * cv.y; acc0.z += w0 * cv.z; acc0.w += w0 * cv.w;
      acc1.x += w1 * cv.x; acc1.y += w1 * cv.y; acc1.z += w1 * cv.z; acc1.w += w1 * cv.w;
      if (ig == 0) {
        const float bkv = bks[hh];
        c1a.x += bkv * cv.x; c1a.y += bkv * cv.y; c1a.z += bkv * cv.z; c1a.w += bkv * cv.w;
      }
    }
    float4* MP4 = (float4*)(ws + OFF_MP);
    const size_t base = (size_t)(b * NHC + hc) * 64;
    MP4[(base + ig * 2)     * 128 + d04 + tj4] = acc0;
    MP4[(base + ig * 2 + 1) * 128 + d04 + tj4] = acc1;
    if (ig == 0) {
      float4* c14 = (float4*)(ws + OFF_C1P);
      c14[(size_t)(b * NHC + hc) * 128 + d04 + tj4] = c1a;
    }
    return;
  }

  // ---- k1 stats ----
  float* XTS = SH;               // swizzled [64][128]
  float* Gs  = SH + 8192;        // [64][64]
  float* wsh = SH + 12288;       // [64]
  float* n2p = SH + 12352;       // [8][128]
  float* d1s = SH + 13376;       // [128]
  float* d2s = SH + 13504;       // [128]

  const int b = idx >> 6;
  const int seg = idx & 63;

  {
    const float4* G4 = (const float4*)(ws + OFF_G);
    #pragma unroll
    for (int p = 0; p < 4; ++p) {
      const int e = p * 256 + t;
      *(float4*)&Gs[e * 4] = G4[e];
    }
  }
  if (t < 64) wsh[t] = ws[OFF_W + t];
  const float bb = ws[OFF_BB];

  // stage X transposed + swizzled
  {
    const float4* src = (const float4*)(hs + ((size_t)b * Ln + (size_t)seg * LT) * Rn);
    #pragma unroll
    for (int k = 0; k < 8; ++k) {
      int f = k * 256 + t;
      float4 v = src[f];
      int l = f >> 4, j0 = (f & 15) << 2;
      XTS[xtidx(j0 + 0, l)] = v.x;
      XTS[xtidx(j0 + 1, l)] = v.y;
      XTS[xtidx(j0 + 2, l)] = v.z;
      XTS[xtidx(j0 + 3, l)] = v.w;
    }
  }
  __syncthreads();

  // phase A: Y[i][l] = sum_k G[i][k]*X[k][l]; n2 partials
  {
    const int i0 = (t & 7) * 8;
    const int lc = t >> 3;              // col4 index, la = lc*4
    const int la = lc * 4;
    float acc[8][4] = {};
    for (int k = 0; k < 64; ++k) {
      const float4 g0 = *(const float4*)&Gs[k * 64 + i0];
      const float4 g1 = *(const float4*)&Gs[k * 64 + i0 + 4];
      const float4 xv = *(const float4*)&XTS[k * 128 + ((lc ^ ((k >> 2) & 7)) << 2)];
      const float ga[8] = {g0.x, g0.y, g0.z, g0.w, g1.x, g1.y, g1.z, g1.w};
      const float xa[4] = {xv.x, xv.y, xv.z, xv.w};
      #pragma unroll
      for (int a = 0; a < 8; ++a)
        #pragma unroll
        for (int lv = 0; lv < 4; ++lv)
          acc[a][lv] += ga[a] * xa[lv];
    }
    #pragma unroll
    for (int lv = 0; lv < 4; ++lv) {
      float s = 0.f;
      #pragma unroll
      for (int a = 0; a < 8; ++a)
        s += XTS[xtidx(i0 + a, la + lv)] * (acc[a][lv] + 2.0f * wsh[i0 + a]);
      n2p[(t & 7) * 128 + la + lv] = s;
    }
  }
  __syncthreads();
  if (t < LT) {
    float n2 = bb;
    #pragma unroll
    for (int p = 0; p < 8; ++p) n2 += n2p[p * 128 + t];
    n2 = fmaxf(n2, 0.0f);
    const float d1 = 1.0f / fmaxf(sqrtf(n2), 1e-12f);
    d1s[t] = d1;
    d2s[t] = d1 * d1;
  }
  __syncthreads();

  float sg1 = 0.f, sg2 = 0.f;
  if (t < 64) {
    float a1 = d1s[t] + d1s[t + 64];
    float a2 = d2s[t] + d2s[t + 64];
    #pragma unroll
    for (int off = 32; off > 0; off >>= 1) {
      a1 += __shfl_down(a1, off, 64);
      a2 += __shfl_down(a2, off, 64);
    }
    sg1 = a1; sg2 = a2;
  }

  // phase B: A1/A2 4x4 per-thread accumulation over the tile
  const int rb = t >> 4;             // xi row-group (rows rb*4 .. +3)
  const int rc = t & 15;             // xj row-group
  const int bi0 = rb * 4;
  const int bj0 = rc * 4;
  float A1a[4][4] = {}, A2a[4][4] = {};
  float u1a[4] = {0.f, 0.f, 0.f, 0.f}, u2a[4] = {0.f, 0.f, 0.f, 0.f};
  for (int l4 = 0; l4 < LT; l4 += 4) {
    const int c4 = l4 >> 2;
    const float4 q1 = *(const float4*)&d1s[l4];
    const float4 q2 = *(const float4*)&d2s[l4];
    const float d1v[4] = {q1.x, q1.y, q1.z, q1.w};
    const float d2v[4] = {q2.x, q2.y, q2.z, q2.w};
    float e1[4][4], e2[4][4], xj[4][4];
    const int swi = (c4 ^ (rb & 7)) << 2;
    const int swj = (c4 ^ (rc & 7)) << 2;
    #pragma unroll
    for (int a = 0; a < 4; ++a) {
      const float4 xv = *(const float4*)&XTS[(bi0 + a) * 128 + swi];
      const float xa[4] = {xv.x, xv.y, xv.z, xv.w};
      #pragma unroll
      for (int lv = 0; lv < 4; ++lv) {
        e1[a][lv] = d1v[lv] * xa[lv];
        e2[a][lv] = d2v[lv] * xa[lv];
      }
    }
    #pragma unroll
    for (int bq = 0; bq < 4; ++bq) {
      const float4 xv = *(const float4*)&XTS[(bj0 + bq) * 128 + swj];
      xj[bq][0] = xv.x; xj[bq][1] = xv.y; xj[bq][2] = xv.z; xj[bq][3] = xv.w;
    }
    #pragma unroll
    for (int a = 0; a < 4; ++a)
      #pragma unroll
      for (int bq = 0; bq < 4; ++bq) {
        float s1 = A1a[a][bq], s2 = A2a[a][bq];
        #pragma unroll
        for (int lv = 0; lv < 4; ++lv) {
          s1 += e1[a][lv] * xj[bq][lv];
          s2 += e2[a][lv] * xj[bq][lv];
        }
        A1a[a][bq] = s1; A2a[a][bq] = s2;
      }
    if (bj0 == 0) {
      #pragma unroll
      for (int a = 0; a < 4; ++a)
        #pragma unroll
        for (int lv = 0; lv < 4; ++lv) {
          u1a[a] += e1[a][lv];
          u2a[a] += e2[a][lv];
        }
    }
  }

  float* P = ws + OFF_STATS + (size_t)idx * PS;
  #pragma unroll
  for (int a = 0; a < 4; ++a)
    #pragma unroll
    for (int bq = 0; bq < 4; ++bq) {
      P[(bi0 + a) * 64 + bj0 + bq] = A1a[a][bq];
      P[4096 + (bi0 + a) * 64 + bj0 + bq] = A2a[a][bq];
    }
  if (bj0 == 0) {
    #pragma unroll
    for (int a = 0; a < 4; ++a) {
      P[8192 + bi0 + a] = u1a[a];
      P[8256 + bi0 + a] = u2a[a];
    }
  }
  if (t == 0) { P[8320] = sg1; P[8321] = sg2; }
}

// ---------------------------------------------------------------------------
// k1b: reduce 64 partials per batch -> A1R, A2R, U1R, U2R, SIG
// grid 256 (= b(8) x sel(2) x q(16)) x 256
__global__ __launch_bounds__(256) void k1b_reduce(float* __restrict__ ws) {
  const int t = threadIdx.x;
  const int blk = blockIdx.x;
  const int b = blk >> 5, sel = (blk >> 4) & 1, q = blk & 15;
  const float* SB = ws + OFF_STATS + (size_t)b * 64 * PS + (size_t)sel * 4096;
  float* dst = ws + (sel ? OFF_A2R : OFF_A1R) + (size_t)b * 4096;
  const int e = q * 256 + t;
  float s = 0.f;
  #pragma unroll 8
  for (int p = 0; p < 64; ++p) s += SB[(size_t)p * PS + e];
  dst[e] = s;
  if (sel == 0 && q == 0) {
    const float* UB = ws + OFF_STATS + (size_t)b * 64 * PS;
    if (t < 64) {
      float s2 = 0.f;
      #pragma unroll 8
      for (int p = 0; p < 64; ++p) s2 += UB[(size_t)p * PS + 8192 + t];
      ws[OFF_U1R + b * 64 + t] = s2;
    } else if (t < 128) {
      const int i = t - 64;
      float s2 = 0.f;
      #pragma unroll 8
      for (int p = 0; p < 64; ++p) s2 += UB[(size_t)p * PS + 8256 + i];
      ws[OFF_U2R + b * 64 + i] = s2;
    } else if (t == 128) {
      float s1 = 0.f, s2 = 0.f;
      for (int p = 0; p < 64; ++p) {
        s1 += UB[(size_t)p * PS + 8320];
        s2 += UB[(size_t)p * PS + 8321];
      }
      ws[OFF_SIG + b * 2] = s1;
      ws[OFF_SIG + b * 2 + 1] = s2;
    }
  }
}

// ---------------------------------------------------------------------------
// k2p: Td = A1 @ Wv - A2 @ M  (M = sum of 4 h-partials)
//      p1 = Wk^T u1, p2 = Wk^T u2, q1 = Wv^T u1, g = u2^T M
// grid 128 (= b(8) x ds(16, 32-wide)) x 256
__global__ __launch_bounds__(256) void k2p_td(const float* __restrict__ Wk,
                                              const float* __restrict__ Wv,
                                              float* __restrict__ ws) {
  __shared__ __align__(16) float A1s[64][66];
  __shared__ __align__(16) float A2s[64][66];
  __shared__ __align__(16) float Wvt[64][36];
  __shared__ __align__(16) float Mt[64][36];
  __shared__ __align__(16) float u1s[64];
  __shared__ __align__(16) float u2s[64];

  const int t = threadIdx.x;
  const int blk = blockIdx.x;
  const int b = blk >> 4;
  const int ds = blk & 15;
  const int d04 = ds * 8;

  const float4* A1R4 = (const float4*)(ws + OFF_A1R + (size_t)b * 4096);
  const float4* A2R4 = (const float4*)(ws + OFF_A2R + (size_t)b * 4096);
  #pragma unroll
  for (int p = 0; p < 4; ++p) {
    const int idx = p * 256 + t;
    const int r = idx >> 4, c0 = (idx & 15) * 4;
    *(float4*)&A1s[r][c0] = A1R4[idx];
    *(float4*)&A2s[r][c0] = A2R4[idx];
  }
  const float4* Wv4 = (const float4*)Wv;
  const float4* MP4 = (const float4*)(ws + OFF_MP);
  #pragma unroll
  for (int p = 0; p < 2; ++p) {
    const int idx = p * 256 + t;
    const int r = idx >> 3, c4 = idx & 7;
    *(float4*)&Wvt[r][c4 * 4] = Wv4[(size_t)r * 128 + d04 + c4];
    float4 m = MP4[((size_t)(b * NHC + 0) * 64 + r) * 128 + d04 + c4];
    #pragma unroll
    for (int q = 1; q < NHC; ++q) {
      const float4 mq = MP4[((size_t)(b * NHC + q) * 64 + r) * 128 + d04 + c4];
      m.x += mq.x; m.y += mq.y; m.z += mq.z; m.w += mq.w;
    }
    *(float4*)&Mt[r][c4 * 4] = m;
  }
  if (t < 16) {
    *(float4*)&u1s[t * 4] = *(const float4*)(ws + OFF_U1R + b * 64 + t * 4);
  } else if (t < 32) {
    const int i = t - 16;
    *(float4*)&u2s[i * 4] = *(const float4*)(ws + OFF_U2R + b * 64 + i * 4);
  }
  __syncthreads();

  const int ig = t >> 3;         // rows i = ig*2, ig*2+1
  const int tj4 = t & 7;
  float4 acc0 = make_float4(0.f, 0.f, 0.f, 0.f);
  float4 acc1 = make_float4(0.f, 0.f, 0.f, 0.f);
  #pragma unroll 8
  for (int j = 0; j < 64; ++j) {
    const float4 wv = *(const float4*)&Wvt[j][tj4 * 4];
    const float4 mv = *(const float4*)&Mt[j][tj4 * 4];
    const float a10 = A1s[ig * 2][j], a20 = A2s[ig * 2][j];
    const float a11 = A1s[ig * 2 + 1][j], a21 = A2s[ig * 2 + 1][j];
    acc0.x += a10 * wv.x - a20 * mv.x; acc0.y += a10 * wv.y - a20 * mv.y;
    acc0.z += a10 * wv.z - a20 * mv.z; acc0.w += a10 * wv.w - a20 * mv.w;
    acc1.x += a11 * wv.x - a21 * mv.x; acc1.y += a11 * wv.y - a21 * mv.y;
    acc1.z += a11 * wv.z - a21 * mv.z; acc1.w += a11 * wv.w - a21 * mv.w;
  }
  float4* Td4 = (float4*)(ws + OFF_TD + (size_t)b * 64 * Hn);
  Td4[(size_t)(ig * 2)     * 128 + d04 + tj4] = acc0;
  Td4[(size_t)(ig * 2 + 1) * 128 + d04 + tj4] = acc1;

  if (t < 32) {
    const int d = ds * 32 + t;
    float q1 = 0.f, g = 0.f;
    #pragma unroll 8
    for (int i = 0; i < 64; ++i) {
      q1 += u1s[i] * Wvt[i][t];
      g  += u2s[i] * Mt[i][t];
    }
    ws[OFF_Q1 + (size_t)b * Hn + d] = q1;
    ws[OFF_GV + (size_t)b * Hn + d] = g;
  } else if (t < 64) {
    const int h = ds * 32 + (t - 32);
    float p1 = 0.f, p2 = 0.f;
    #pragma unroll 8
    for (int i = 0; i < 64; ++i) {
      const float wv = Wk[(size_t)i * Hn + h];
      p1 += wv * u1s[i];
      p2 += wv * u2s[i];
    }
    ws[OFF_P1 + (size_t)b * Hn + h] = p1;
    ws[OFF_P2 + (size_t)b * Hn + h] = p2;
  }
}

// ---------------------------------------------------------------------------
// k4: out = C + Wk^T Td + (p1 + sig1*bk) (x) bv + bk (x) (q1 - g - sig2*c1) - p2 (x) c1
// grid 512 (= b(8) x hstrip(8, 64-wide) x dstrip(8, 64-wide)) x 256
__global__ __launch_bounds__(256) void k4_out(const float* __restrict__ C,
                                              const float* __restrict__ Wk,
                                              const float* __restrict__ bk,
                                              const float* __restrict__ bv,
                                              const float* __restrict__ ws,
                                              float* __restrict__ out) {
  __shared__ __align__(16) float Tds[64][68];
  __shared__ __align__(16) float Wks[64][68];
  __shared__ float phs[64], bks[64], p2s[64];
  __shared__ float bvs[64], terms[64], c1s[64];

  const int t = threadIdx.x;
  const int blk = blockIdx.x;
  const int b = blk >> 6;
  const int rem = blk & 63;
  const int hs0 = (rem >> 3) * 64;
  const int d04 = (rem & 7) * 16;               // float4 offset of 64-wide d strip
  const float sg1 = ws[OFF_SIG + b * 2];
  const float sg2 = ws[OFF_SIG + b * 2 + 1];

  const float4* TdG4 = (const float4*)(ws + OFF_TD + (size_t)b * 64 * Hn);
  const float4* Wk4 = (const float4*)Wk;
  #pragma unroll
  for (int p = 0; p < 4; ++p) {
    const int e = p * 256 + t;                  // 1024 float4 (64 x 16)
    const int r = e >> 4, c4 = e & 15;
    *(float4*)&Tds[r][c4 * 4] = TdG4[(size_t)r * 128 + d04 + c4];
    *(float4*)&Wks[r][c4 * 4] = Wk4[(size_t)r * 128 + (hs0 >> 2) + c4];
  }
  if (t < 64) {
    const int h = hs0 + t;
    const float bkv = bk[h];
    bks[t] = bkv;
    phs[t] = ws[OFF_P1 + (size_t)b * Hn + h] + sg1 * bkv;
    p2s[t] = ws[OFF_P2 + (size_t)b * Hn + h];
  } else if (t < 128) {
    const int dd = t - 64;
    const int d = d04 * 4 + dd;
    float c1 = 0.f;
    #pragma unroll
    for (int q = 0; q < NHC; ++q)
      c1 += ws[OFF_C1P + (size_t)(b * NHC + q) * Hn + d];
    c1s[dd] = c1;
    bvs[dd] = bv[d];
    terms[dd] = ws[OFF_Q1 + (size_t)b * Hn + d] - ws[OFF_GV + (size_t)b * Hn + d] - sg2 * c1;
  }
  __syncthreads();

  const int ti = t >> 4;   // rows hh = ti*4 .. +4
  const int tj4 = t & 15;  // d float4 within strip
  float4 acc[4];
  #pragma unroll
  for (int a = 0; a < 4; ++a) acc[a] = make_float4(0.f, 0.f, 0.f, 0.f);
  for (int j = 0; j < 64; ++j) {
    const float4 td4 = *(const float4*)&Tds[j][tj4 * 4];
    #pragma unroll
    for (int a = 0; a < 4; ++a) {
      const float wv = Wks[j][ti * 4 + a];
      acc[a].x += wv * td4.x; acc[a].y += wv * td4.y;
      acc[a].z += wv * td4.z; acc[a].w += wv * td4.w;
    }
  }

  const float4* C4b = (const float4*)(C + (size_t)b * Hn * Hn);
  float4* out4 = (float4*)(out + (size_t)b * Hn * Hn);
  const float4 bv4 = *(const float4*)&bvs[tj4 * 4];
  const float4 tm4 = *(const float4*)&terms[tj4 * 4];
  const float4 c14 = *(const float4*)&c1s[tj4 * 4];
  #pragma unroll
  for (int a = 0; a < 4; ++a) {
    const int hh = ti * 4 + a;
    const int h = hs0 + hh;
    const float4 c = C4b[(size_t)h * 128 + d04 + tj4];
    const float ph = phs[hh], bkh = bks[hh], p2h = p2s[hh];
    float4 o;
    o.x = c.x + acc[a].x + ph * bv4.x + bkh * tm4.x - p2h * c14.x;
    o.y = c.y + acc[a].y + ph * bv4.y + bkh * tm4.y - p2h * c14.y;
    o.z = c.z + acc[a].z + ph * bv4.z + bkh * tm4.z - p2h * c14.z;
    o.w = c.w + acc[a].w + ph * bv4.w + bkh * tm4.w - p2h * c14.w;
    out4[(size_t)h * 128 + d04 + tj4] = o;
  }
}

// ---------------------------------------------------------------------------
extern "C" void kernel_launch(void* const* d_in, const int* in_sizes, int n_in,
                              void* d_out, int out_size, void* d_ws, size_t ws_size,
                              hipStream_t stream) {
  const float* hs = (const float*)d_in[0];
  const float* C  = (const float*)d_in[1];
  const float* Wk = (const float*)d_in[2];
  const float* bk = (const float*)d_in[3];
  const float* Wv = (const float*)d_in[4];
  const float* bv = (const float*)d_in[5];
  float* out = (float*)d_out;
  float* ws = (float*)d_ws;
  (void)in_sizes; (void)n_in; (void)out_size; (void)ws_size;

  hipLaunchKernelGGL(kG_pre,     dim3(65),   dim3(256), 0, stream, Wk, bk, ws);
  hipLaunchKernelGGL(k1M,        dim3(1024), dim3(256), 0, stream, hs, Wk, bk, C, ws);
  hipLaunchKernelGGL(k1b_reduce, dim3(256),  dim3(256), 0, stream, ws);
  hipLaunchKernelGGL(k2p_td,     dim3(128),  dim3(256), 0, stream, Wk, Wv, ws);
  hipLaunchKernelGGL(k4_out,     dim3(512),  dim3(256), 0, stream, C, Wk, bk, bv, ws, out);
}

// Round 6
// 83.828 us; speedup vs baseline: 1.1175x; 1.1175x over previous
//
#include <hip/hip_runtime.h>
#include <math.h>

namespace {
constexpr int Bn = 8;
constexpr int Ln = 8192;
constexpr int Rn = 64;
constexpr int Hn = 512;
constexpr int LT = 128;
constexpr int NSEG = Ln / LT;            // 64 segments per batch
constexpr int NK1 = Bn * NSEG;           // 512 k1 blocks
constexpr int NHC = 4;                   // M h-chunks (128 h each)

// workspace float offsets
constexpr size_t PS        = 8352;       // per-k1-block partial stride
constexpr size_t OFF_G     = 0;                                   // 64x64
constexpr size_t OFF_W     = 4096;                                // 64
constexpr size_t OFF_BB    = 4160;                                // 1 (+pad)
constexpr size_t OFF_STATS = 4224;                                // NK1 * PS
constexpr size_t OFF_A1R   = OFF_STATS + (size_t)NK1 * PS;        // B*4096
constexpr size_t OFF_A2R   = OFF_A1R + (size_t)Bn * 4096;         // B*4096
constexpr size_t OFF_U1R   = OFF_A2R + (size_t)Bn * 4096;         // B*64
constexpr size_t OFF_U2R   = OFF_U1R + (size_t)Bn * 64;           // B*64
constexpr size_t OFF_SIG   = OFF_U2R + (size_t)Bn * 64;           // B*2 (pad 64)
constexpr size_t OFF_MP    = OFF_SIG + 64;                        // B*NHC*64*H (M h-partials)
constexpr size_t OFF_C1P   = OFF_MP + (size_t)Bn * NHC * 64 * Hn; // B*NHC*H
constexpr size_t OFF_TD    = OFF_C1P + (size_t)Bn * NHC * Hn;     // B*64*H
constexpr size_t OFF_P1    = OFF_TD + (size_t)Bn * 64 * Hn;       // B*H
constexpr size_t OFF_P2    = OFF_P1 + (size_t)Bn * Hn;            // B*H
constexpr size_t OFF_Q1    = OFF_P2 + (size_t)Bn * Hn;            // B*H
constexpr size_t OFF_GV    = OFF_Q1 + (size_t)Bn * Hn;            // B*H     (g = u2^T M)
}

// swizzled XT index: row-stride 128, col4 XOR'd with (r>>2)&7 -> all k1 LDS
// accesses are <=2-way bank aliased (free on CDNA4).
__device__ __forceinline__ int xtidx(int r, int l) {
  return r * 128 + ((((l >> 2) ^ ((r >> 2) & 7)) << 2) | (l & 3));
}

// ---------------------------------------------------------------------------
// kA: blocks 0..63  : G[i][j] = Wk_i . Wk_j  (block = row i, 4 lanes per dot)
//     block 64      : w = Wk*bk, bb = bk.bk
//     blocks 65..576: M h-partials: MP[b][hc] = Wk[:, hc*128:+128] @ C[chunk, dstrip]
//                     + c1 partials C1P[b][hc] = bk_chunk^T C_chunk
// grid 577 x 256
__global__ __launch_bounds__(256) void kA_pre(const float* __restrict__ Wk,
                                              const float* __restrict__ bk,
                                              const float* __restrict__ C,
                                              float* __restrict__ ws) {
  const int t = threadIdx.x;
  const int blk = blockIdx.x;

  if (blk < 64) {
    // G row blk
    const int j = t >> 2, kq = t & 3;
    const float4* a4 = (const float4*)(Wk + (size_t)blk * Hn) + kq * 32;
    const float4* b4 = (const float4*)(Wk + (size_t)j * Hn) + kq * 32;
    float s0 = 0.f, s1 = 0.f, s2 = 0.f, s3 = 0.f;
    #pragma unroll 8
    for (int h = 0; h < 32; ++h) {
      const float4 x = a4[h], y = b4[h];
      s0 += x.x * y.x; s1 += x.y * y.y; s2 += x.z * y.z; s3 += x.w * y.w;
    }
    float s = (s0 + s1) + (s2 + s3);
    s += __shfl_down(s, 2, 4);
    s += __shfl_down(s, 1, 4);
    if (kq == 0) ws[OFF_G + blk * 64 + j] = s;
    return;
  }
  if (blk == 64) {
    const int i = t >> 2, kq = t & 3;
    const float4* a4 = (const float4*)(Wk + (size_t)i * Hn) + kq * 32;
    const float4* b4 = (const float4*)bk + kq * 32;
    float s0 = 0.f, s1 = 0.f, s2 = 0.f, s3 = 0.f;
    #pragma unroll 8
    for (int h = 0; h < 32; ++h) {
      const float4 x = a4[h], y = b4[h];
      s0 += x.x * y.x; s1 += x.y * y.y; s2 += x.z * y.z; s3 += x.w * y.w;
    }
    float s = (s0 + s1) + (s2 + s3);
    s += __shfl_down(s, 2, 4);
    s += __shfl_down(s, 1, 4);
    if (kq == 0) ws[OFF_W + i] = s;
    if (t < 4) {
      const float4* b4b = (const float4*)bk + t * 32;
      float q0 = 0.f, q1 = 0.f, q2 = 0.f, q3 = 0.f;
      #pragma unroll 8
      for (int h = 0; h < 32; ++h) {
        const float4 y = b4b[h];
        q0 += y.x * y.x; q1 += y.y * y.y; q2 += y.z * y.z; q3 += y.w * y.w;
      }
      float q = (q0 + q1) + (q2 + q3);
      q += __shfl_down(q, 2, 4);
      q += __shfl_down(q, 1, 4);
      if (t == 0) ws[OFF_BB] = q;
    }
    return;
  }

  // ---- M / c1 partials ----
  __shared__ __align__(16) float Wks[64][132];  // [i][h within 128-chunk]
  __shared__ __align__(16) float Cs[128][36];   // [h within chunk][d within strip]
  __shared__ __align__(16) float bks[128];

  const int m = blk - 65;
  const int b = m >> 6;
  const int rem = m & 63;
  const int hc = rem >> 4;
  const int ds = rem & 15;
  const int h0 = hc * 128;
  const int d04 = ds * 8;                       // float4 offset of 32-wide strip

  const float4* Wk4 = (const float4*)Wk;
  const float4* C4b = (const float4*)(C + (size_t)b * Hn * Hn);
  #pragma unroll
  for (int p = 0; p < 8; ++p) {
    const int e = p * 256 + t;                  // 2048 float4 (64 x 32)
    const int r = e >> 5, c4 = e & 31;
    *(float4*)&Wks[r][c4 * 4] = Wk4[(size_t)r * 128 + (h0 >> 2) + c4];
  }
  #pragma unroll
  for (int p = 0; p < 4; ++p) {
    const int e = p * 256 + t;                  // 1024 float4 (128 x 8)
    const int r = e >> 3, c4 = e & 7;
    *(float4*)&Cs[r][c4 * 4] = C4b[(size_t)(h0 + r) * 128 + d04 + c4];
  }
  if (t < 32) *(float4*)&bks[t * 4] = *(const float4*)&bk[h0 + t * 4];
  __syncthreads();

  const int ig = t >> 3;                        // rows 2ig, 2ig+1
  const int tj4 = t & 7;
  float4 acc0 = make_float4(0.f, 0.f, 0.f, 0.f);
  float4 acc1 = make_float4(0.f, 0.f, 0.f, 0.f);
  float4 c1a  = make_float4(0.f, 0.f, 0.f, 0.f);
  #pragma unroll 8
  for (int hh = 0; hh < 128; ++hh) {
    const float4 cv = *(const float4*)&Cs[hh][tj4 * 4];
    const float w0 = Wks[ig * 2][hh];
    const float w1 = Wks[ig * 2 + 1][hh];
    acc0.x += w0 * cv.x; acc0.y += w0 * cv.y; acc0.z += w0 * cv.z; acc0.w += w0 * cv.w;
    acc1.x += w1 * cv.x; acc1.y += w1 * cv.y; acc1.z += w1 * cv.z; acc1.w += w1 * cv.w;
    if (ig == 0) {
      const float bkv = bks[hh];
      c1a.x += bkv * cv.x; c1a.y += bkv * cv.y; c1a.z += bkv * cv.z; c1a.w += bkv * cv.w;
    }
  }

  float4* MP4 = (float4*)(ws + OFF_MP);
  const size_t base = (size_t)(b * NHC + hc) * 64;
  MP4[(base + ig * 2)     * 128 + d04 + tj4] = acc0;
  MP4[(base + ig * 2 + 1) * 128 + d04 + tj4] = acc1;
  if (ig == 0) {
    float4* c14 = (float4*)(ws + OFF_C1P);
    c14[(size_t)(b * NHC + hc) * 128 + d04 + tj4] = c1a;
  }
}

// ---------------------------------------------------------------------------
// k1: per 128-row tile: row norms via x*G*x + 2x.w + bb (G from GLOBAL,
//     n2 reduced by shfl_xor butterfly), then A1/A2/u/sig partials.
// LDS ~34KB -> 4 blocks/CU. grid 512 (= 8 b x 64 seg) x 256
__global__ __launch_bounds__(256, 4) void k1_stats(const float* __restrict__ hs,
                                                   float* __restrict__ ws) {
  __shared__ __align__(16) float XTS[8192];   // swizzled [64][128], 32KB
  __shared__ __align__(16) float d1s[LT];
  __shared__ __align__(16) float d2s[LT];
  __shared__ __align__(16) float wsh[64];

  const int t = threadIdx.x;
  const int idx = blockIdx.x;
  const int b = idx >> 6;
  const int seg = idx & 63;

  if (t < 64) wsh[t] = ws[OFF_W + t];
  const float bb = ws[OFF_BB];

  // stage X transposed + swizzled
  {
    const float4* src = (const float4*)(hs + ((size_t)b * Ln + (size_t)seg * LT) * Rn);
    #pragma unroll
    for (int k = 0; k < 8; ++k) {
      int f = k * 256 + t;
      float4 v = src[f];
      int l = f >> 4, j0 = (f & 15) << 2;
      XTS[xtidx(j0 + 0, l)] = v.x;
      XTS[xtidx(j0 + 1, l)] = v.y;
      XTS[xtidx(j0 + 2, l)] = v.z;
      XTS[xtidx(j0 + 3, l)] = v.w;
    }
  }
  __syncthreads();

  // phase A: Y[i][l] = sum_k G[i][k]*X[k][l]; G streamed from global (L1/L2)
  {
    const int i0 = (t & 7) * 8;
    const int lc = t >> 3;              // col4 index
    const int la = lc * 4;
    const float* Gg = ws + OFF_G;
    float acc[8][4] = {};
    for (int k = 0; k < 64; ++k) {
      const float4 g0 = *(const float4*)(Gg + (size_t)k * 64 + i0);
      const float4 g1 = *(const float4*)(Gg + (size_t)k * 64 + i0 + 4);
      const float4 xv = *(const float4*)&XTS[k * 128 + ((lc ^ ((k >> 2) & 7)) << 2)];
      const float ga[8] = {g0.x, g0.y, g0.z, g0.w, g1.x, g1.y, g1.z, g1.w};
      const float xa[4] = {xv.x, xv.y, xv.z, xv.w};
      #pragma unroll
      for (int a = 0; a < 8; ++a)
        #pragma unroll
        for (int lv = 0; lv < 4; ++lv)
          acc[a][lv] += ga[a] * xa[lv];
    }
    // per-thread n2 partial over i-slice, then butterfly over the 8 slices
    float s[4];
    #pragma unroll
    for (int lv = 0; lv < 4; ++lv) {
      float v = 0.f;
      #pragma unroll
      for (int a = 0; a < 8; ++a)
        v += XTS[xtidx(i0 + a, la + lv)] * (acc[a][lv] + 2.0f * wsh[i0 + a]);
      s[lv] = v;
    }
    #pragma unroll
    for (int off = 1; off <= 4; off <<= 1) {
      #pragma unroll
      for (int lv = 0; lv < 4; ++lv) s[lv] += __shfl_xor(s[lv], off, 64);
    }
    if ((t & 7) == 0) {
      #pragma unroll
      for (int lv = 0; lv < 4; ++lv) {
        float n2 = fmaxf(bb + s[lv], 0.0f);
        const float d1 = 1.0f / fmaxf(sqrtf(n2), 1e-12f);
        d1s[la + lv] = d1;
        d2s[la + lv] = d1 * d1;
      }
    }
  }
  __syncthreads();

  float sg1 = 0.f, sg2 = 0.f;
  if (t < 64) {
    float a1 = d1s[t] + d1s[t + 64];
    float a2 = d2s[t] + d2s[t + 64];
    #pragma unroll
    for (int off = 32; off > 0; off >>= 1) {
      a1 += __shfl_down(a1, off, 64);
      a2 += __shfl_down(a2, off, 64);
    }
    sg1 = a1; sg2 = a2;
  }

  // phase B: A1/A2 4x4 per-thread accumulation over the tile
  const int rb = t >> 4;             // xi row-group
  const int rc = t & 15;             // xj row-group
  const int bi0 = rb * 4;
  const int bj0 = rc * 4;
  float A1a[4][4] = {}, A2a[4][4] = {};
  float u1a[4] = {0.f, 0.f, 0.f, 0.f}, u2a[4] = {0.f, 0.f, 0.f, 0.f};
  for (int l4 = 0; l4 < LT; l4 += 4) {
    const int c4 = l4 >> 2;
    const float4 q1 = *(const float4*)&d1s[l4];
    const float4 q2 = *(const float4*)&d2s[l4];
    const float d1v[4] = {q1.x, q1.y, q1.z, q1.w};
    const float d2v[4] = {q2.x, q2.y, q2.z, q2.w};
    float e1[4][4], e2[4][4], xj[4][4];
    const int swi = (c4 ^ (rb & 7)) << 2;
    const int swj = (c4 ^ (rc & 7)) << 2;
    #pragma unroll
    for (int a = 0; a < 4; ++a) {
      const float4 xv = *(const float4*)&XTS[(bi0 + a) * 128 + swi];
      const float xa[4] = {xv.x, xv.y, xv.z, xv.w};
      #pragma unroll
      for (int lv = 0; lv < 4; ++lv) {
        e1[a][lv] = d1v[lv] * xa[lv];
        e2[a][lv] = d2v[lv] * xa[lv];
      }
    }
    #pragma unroll
    for (int bq = 0; bq < 4; ++bq) {
      const float4 xv = *(const float4*)&XTS[(bj0 + bq) * 128 + swj];
      xj[bq][0] = xv.x; xj[bq][1] = xv.y; xj[bq][2] = xv.z; xj[bq][3] = xv.w;
    }
    #pragma unroll
    for (int a = 0; a < 4; ++a)
      #pragma unroll
      for (int bq = 0; bq < 4; ++bq) {
        float s1 = A1a[a][bq], s2 = A2a[a][bq];
        #pragma unroll
        for (int lv = 0; lv < 4; ++lv) {
          s1 += e1[a][lv] * xj[bq][lv];
          s2 += e2[a][lv] * xj[bq][lv];
        }
        A1a[a][bq] = s1; A2a[a][bq] = s2;
      }
    if (bj0 == 0) {
      #pragma unroll
      for (int a = 0; a < 4; ++a)
        #pragma unroll
        for (int lv = 0; lv < 4; ++lv) {
          u1a[a] += e1[a][lv];
          u2a[a] += e2[a][lv];
        }
    }
  }

  float* P = ws + OFF_STATS + (size_t)idx * PS;
  #pragma unroll
  for (int a = 0; a < 4; ++a)
    #pragma unroll
    for (int bq = 0; bq < 4; ++bq) {
      P[(bi0 + a) * 64 + bj0 + bq] = A1a[a][bq];
      P[4096 + (bi0 + a) * 64 + bj0 + bq] = A2a[a][bq];
    }
  if (bj0 == 0) {
    #pragma unroll
    for (int a = 0; a < 4; ++a) {
      P[8192 + bi0 + a] = u1a[a];
      P[8256 + bi0 + a] = u2a[a];
    }
  }
  if (t == 0) { P[8320] = sg1; P[8321] = sg2; }
}

// ---------------------------------------------------------------------------
// k1b: reduce 64 partials per batch -> A1R, A2R, U1R, U2R, SIG
// grid 256 (= b(8) x sel(2) x q(16)) x 256
__global__ __launch_bounds__(256) void k1b_reduce(float* __restrict__ ws) {
  const int t = threadIdx.x;
  const int blk = blockIdx.x;
  const int b = blk >> 5, sel = (blk >> 4) & 1, q = blk & 15;
  const float* SB = ws + OFF_STATS + (size_t)b * 64 * PS + (size_t)sel * 4096;
  float* dst = ws + (sel ? OFF_A2R : OFF_A1R) + (size_t)b * 4096;
  const int e = q * 256 + t;
  float s = 0.f;
  #pragma unroll 8
  for (int p = 0; p < 64; ++p) s += SB[(size_t)p * PS + e];
  dst[e] = s;
  if (sel == 0 && q == 0) {
    const float* UB = ws + OFF_STATS + (size_t)b * 64 * PS;
    if (t < 64) {
      float s2 = 0.f;
      #pragma unroll 8
      for (int p = 0; p < 64; ++p) s2 += UB[(size_t)p * PS + 8192 + t];
      ws[OFF_U1R + b * 64 + t] = s2;
    } else if (t < 128) {
      const int i = t - 64;
      float s2 = 0.f;
      #pragma unroll 8
      for (int p = 0; p < 64; ++p) s2 += UB[(size_t)p * PS + 8256 + i];
      ws[OFF_U2R + b * 64 + i] = s2;
    } else if (t == 128) {
      float s1 = 0.f, s2 = 0.f;
      for (int p = 0; p < 64; ++p) {
        s1 += UB[(size_t)p * PS + 8320];
        s2 += UB[(size_t)p * PS + 8321];
      }
      ws[OFF_SIG + b * 2] = s1;
      ws[OFF_SIG + b * 2 + 1] = s2;
    }
  }
}

// ---------------------------------------------------------------------------
// k2p: Td = A1 @ Wv - A2 @ M  (M = sum of 4 h-partials)
//      p1 = Wk^T u1, p2 = Wk^T u2, q1 = Wv^T u1, g = u2^T M
// grid 128 (= b(8) x ds(16, 32-wide)) x 256
__global__ __launch_bounds__(256) void k2p_td(const float* __restrict__ Wk,
                                              const float* __restrict__ Wv,
                                              float* __restrict__ ws) {
  __shared__ __align__(16) float A1s[64][66];
  __shared__ __align__(16) float A2s[64][66];
  __shared__ __align__(16) float Wvt[64][36];
  __shared__ __align__(16) float Mt[64][36];
  __shared__ __align__(16) float u1s[64];
  __shared__ __align__(16) float u2s[64];

  const int t = threadIdx.x;
  const int blk = blockIdx.x;
  const int b = blk >> 4;
  const int ds = blk & 15;
  const int d04 = ds * 8;

  const float4* A1R4 = (const float4*)(ws + OFF_A1R + (size_t)b * 4096);
  const float4* A2R4 = (const float4*)(ws + OFF_A2R + (size_t)b * 4096);
  #pragma unroll
  for (int p = 0; p < 4; ++p) {
    const int idx = p * 256 + t;
    const int r = idx >> 4, c0 = (idx & 15) * 4;
    *(float4*)&A1s[r][c0] = A1R4[idx];
    *(float4*)&A2s[r][c0] = A2R4[idx];
  }
  const float4* Wv4 = (const float4*)Wv;
  const float4* MP4 = (const float4*)(ws + OFF_MP);
  #pragma unroll
  for (int p = 0; p < 2; ++p) {
    const int idx = p * 256 + t;
    const int r = idx >> 3, c4 = idx & 7;
    *(float4*)&Wvt[r][c4 * 4] = Wv4[(size_t)r * 128 + d04 + c4];
    float4 m = MP4[((size_t)(b * NHC + 0) * 64 + r) * 128 + d04 + c4];
    #pragma unroll
    for (int q = 1; q < NHC; ++q) {
      const float4 mq = MP4[((size_t)(b * NHC + q) * 64 + r) * 128 + d04 + c4];
      m.x += mq.x; m.y += mq.y; m.z += mq.z; m.w += mq.w;
    }
    *(float4*)&Mt[r][c4 * 4] = m;
  }
  if (t < 16) {
    *(float4*)&u1s[t * 4] = *(const float4*)(ws + OFF_U1R + b * 64 + t * 4);
  } else if (t < 32) {
    const int i = t - 16;
    *(float4*)&u2s[i * 4] = *(const float4*)(ws + OFF_U2R + b * 64 + i * 4);
  }
  __syncthreads();

  const int ig = t >> 3;         // rows i = ig*2, ig*2+1
  const int tj4 = t & 7;
  float4 acc0 = make_float4(0.f, 0.f, 0.f, 0.f);
  float4 acc1 = make_float4(0.f, 0.f, 0.f, 0.f);
  #pragma unroll 8
  for (int j = 0; j < 64; ++j) {
    const float4 wv = *(const float4*)&Wvt[j][tj4 * 4];
    const float4 mv = *(const float4*)&Mt[j][tj4 * 4];
    const float a10 = A1s[ig * 2][j], a20 = A2s[ig * 2][j];
    const float a11 = A1s[ig * 2 + 1][j], a21 = A2s[ig * 2 + 1][j];
    acc0.x += a10 * wv.x - a20 * mv.x; acc0.y += a10 * wv.y - a20 * mv.y;
    acc0.z += a10 * wv.z - a20 * mv.z; acc0.w += a10 * wv.w - a20 * mv.w;
    acc1.x += a11 * wv.x - a21 * mv.x; acc1.y += a11 * wv.y - a21 * mv.y;
    acc1.z += a11 * wv.z - a21 * mv.z; acc1.w += a11 * wv.w - a21 * mv.w;
  }
  float4* Td4 = (float4*)(ws + OFF_TD + (size_t)b * 64 * Hn);
  Td4[(size_t)(ig * 2)     * 128 + d04 + tj4] = acc0;
  Td4[(size_t)(ig * 2 + 1) * 128 + d04 + tj4] = acc1;

  if (t < 32) {
    const int d = ds * 32 + t;
    float q1 = 0.f, g = 0.f;
    #pragma unroll 8
    for (int i = 0; i < 64; ++i) {
      q1 += u1s[i] * Wvt[i][t];
      g  += u2s[i] * Mt[i][t];
    }
    ws[OFF_Q1 + (size_t)b * Hn + d] = q1;
    ws[OFF_GV + (size_t)b * Hn + d] = g;
  } else if (t < 64) {
    const int h = ds * 32 + (t - 32);
    float p1 = 0.f, p2 = 0.f;
    #pragma unroll 8
    for (int i = 0; i < 64; ++i) {
      const float wv = Wk[(size_t)i * Hn + h];
      p1 += wv * u1s[i];
      p2 += wv * u2s[i];
    }
    ws[OFF_P1 + (size_t)b * Hn + h] = p1;
    ws[OFF_P2 + (size_t)b * Hn + h] = p2;
  }
}

// ---------------------------------------------------------------------------
// k4: out = C + Wk^T Td + (p1 + sig1*bk) (x) bv + bk (x) (q1 - g - sig2*c1) - p2 (x) c1
// grid 512 (= b(8) x hstrip(8, 64-wide) x dstrip(8, 64-wide)) x 256
__global__ __launch_bounds__(256) void k4_out(const float* __restrict__ C,
                                              const float* __restrict__ Wk,
                                              const float* __restrict__ bk,
                                              const float* __restrict__ bv,
                                              const float* __restrict__ ws,
                                              float* __restrict__ out) {
  __shared__ __align__(16) float Tds[64][68];
  __shared__ __align__(16) float Wks[64][68];
  __shared__ float phs[64], bks[64], p2s[64];
  __shared__ float bvs[64], terms[64], c1s[64];

  const int t = threadIdx.x;
  const int blk = blockIdx.x;
  const int b = blk >> 6;
  const int rem = blk & 63;
  const int hs0 = (rem >> 3) * 64;
  const int d04 = (rem & 7) * 16;               // float4 offset of 64-wide d strip
  const float sg1 = ws[OFF_SIG + b * 2];
  const float sg2 = ws[OFF_SIG + b * 2 + 1];

  const float4* TdG4 = (const float4*)(ws + OFF_TD + (size_t)b * 64 * Hn);
  const float4* Wk4 = (const float4*)Wk;
  #pragma unroll
  for (int p = 0; p < 4; ++p) {
    const int e = p * 256 + t;                  // 1024 float4 (64 x 16)
    const int r = e >> 4, c4 = e & 15;
    *(float4*)&Tds[r][c4 * 4] = TdG4[(size_t)r * 128 + d04 + c4];
    *(float4*)&Wks[r][c4 * 4] = Wk4[(size_t)r * 128 + (hs0 >> 2) + c4];
  }
  if (t < 64) {
    const int h = hs0 + t;
    const float bkv = bk[h];
    bks[t] = bkv;
    phs[t] = ws[OFF_P1 + (size_t)b * Hn + h] + sg1 * bkv;
    p2s[t] = ws[OFF_P2 + (size_t)b * Hn + h];
  } else if (t < 128) {
    const int dd = t - 64;
    const int d = d04 * 4 + dd;
    float c1 = 0.f;
    #pragma unroll
    for (int q = 0; q < NHC; ++q)
      c1 += ws[OFF_C1P + (size_t)(b * NHC + q) * Hn + d];
    c1s[dd] = c1;
    bvs[dd] = bv[d];
    terms[dd] = ws[OFF_Q1 + (size_t)b * Hn + d] - ws[OFF_GV + (size_t)b * Hn + d] - sg2 * c1;
  }
  __syncthreads();

  const int ti = t >> 4;   // rows hh = ti*4 .. +4
  const int tj4 = t & 15;  // d float4 within strip
  float4 acc[4];
  #pragma unroll
  for (int a = 0; a < 4; ++a) acc[a] = make_float4(0.f, 0.f, 0.f, 0.f);
  for (int j = 0; j < 64; ++j) {
    const float4 td4 = *(const float4*)&Tds[j][tj4 * 4];
    #pragma unroll
    for (int a = 0; a < 4; ++a) {
      const float wv = Wks[j][ti * 4 + a];
      acc[a].x += wv * td4.x; acc[a].y += wv * td4.y;
      acc[a].z += wv * td4.z; acc[a].w += wv * td4.w;
    }
  }

  const float4* C4b = (const float4*)(C + (size_t)b * Hn * Hn);
  float4* out4 = (float4*)(out + (size_t)b * Hn * Hn);
  const float4 bv4 = *(const float4*)&bvs[tj4 * 4];
  const float4 tm4 = *(const float4*)&terms[tj4 * 4];
  const float4 c14 = *(const float4*)&c1s[tj4 * 4];
  #pragma unroll
  for (int a = 0; a < 4; ++a) {
    const int hh = ti * 4 + a;
    const int h = hs0 + hh;
    const float4 c = C4b[(size_t)h * 128 + d04 + tj4];
    const float ph = phs[hh], bkh = bks[hh], p2h = p2s[hh];
    float4 o;
    o.x = c.x + acc[a].x + ph * bv4.x + bkh * tm4.x - p2h * c14.x;
    o.y = c.y + acc[a].y + ph * bv4.y + bkh * tm4.y - p2h * c14.y;
    o.z = c.z + acc[a].z + ph * bv4.z + bkh * tm4.z - p2h * c14.z;
    o.w = c.w + acc[a].w + ph * bv4.w + bkh * tm4.w - p2h * c14.w;
    out4[(size_t)h * 128 + d04 + tj4] = o;
  }
}

// ---------------------------------------------------------------------------
extern "C" void kernel_launch(void* const* d_in, const int* in_sizes, int n_in,
                              void* d_out, int out_size, void* d_ws, size_t ws_size,
                              hipStream_t stream) {
  const float* hs = (const float*)d_in[0];
  const float* C  = (const float*)d_in[1];
  const float* Wk = (const float*)d_in[2];
  const float* bk = (const float*)d_in[3];
  const float* Wv = (const float*)d_in[4];
  const float* bv = (const float*)d_in[5];
  float* out = (float*)d_out;
  float* ws = (float*)d_ws;
  (void)in_sizes; (void)n_in; (void)out_size; (void)ws_size;

  hipLaunchKernelGGL(kA_pre,     dim3(577), dim3(256), 0, stream, Wk, bk, C, ws);
  hipLaunchKernelGGL(k1_stats,   dim3(512), dim3(256), 0, stream, hs, ws);
  hipLaunchKernelGGL(k1b_reduce, dim3(256), dim3(256), 0, stream, ws);
  hipLaunchKernelGGL(k2p_td,     dim3(128), dim3(256), 0, stream, Wk, Wv, ws);
  hipLaunchKernelGGL(k4_out,     dim3(512), dim3(256), 0, stream, C, Wk, bk, bv, ws, out);
}

// Round 7
// 81.315 us; speedup vs baseline: 1.1520x; 1.0309x over previous
//
#include <hip/hip_runtime.h>
#include <math.h>

namespace {
constexpr int Bn = 8;
constexpr int Ln = 8192;
constexpr int Rn = 64;
constexpr int Hn = 512;
constexpr int LT = 128;
constexpr int NSEG = Ln / LT;            // 64 segments per batch
constexpr int NK1 = Bn * NSEG;           // 512 k1 blocks
constexpr int NHC = 4;                   // M h-chunks (128 h each)

// workspace float offsets
constexpr size_t PS        = 8352;       // per-k1-block partial stride
constexpr size_t OFF_G     = 0;                                   // 64x64
constexpr size_t OFF_W     = 4096;                                // 64
constexpr size_t OFF_BB    = 4160;                                // 1 (+pad)
constexpr size_t OFF_STATS = 4224;                                // NK1 * PS
constexpr size_t OFF_A1R   = OFF_STATS + (size_t)NK1 * PS;        // B*4096
constexpr size_t OFF_A2R   = OFF_A1R + (size_t)Bn * 4096;         // B*4096
constexpr size_t OFF_U1R   = OFF_A2R + (size_t)Bn * 4096;         // B*64
constexpr size_t OFF_U2R   = OFF_U1R + (size_t)Bn * 64;           // B*64
constexpr size_t OFF_SIG   = OFF_U2R + (size_t)Bn * 64;           // B*2 (pad 64)
constexpr size_t OFF_MP    = OFF_SIG + 64;                        // B*NHC*64*H (M h-partials)
constexpr size_t OFF_C1P   = OFF_MP + (size_t)Bn * NHC * 64 * Hn; // B*NHC*H
constexpr size_t OFF_TD    = OFF_C1P + (size_t)Bn * NHC * Hn;     // B*64*H
constexpr size_t OFF_P1    = OFF_TD + (size_t)Bn * 64 * Hn;       // B*H
constexpr size_t OFF_P2    = OFF_P1 + (size_t)Bn * Hn;            // B*H
constexpr size_t OFF_Q1    = OFF_P2 + (size_t)Bn * Hn;            // B*H
constexpr size_t OFF_GV    = OFF_Q1 + (size_t)Bn * Hn;            // B*H     (g = u2^T M)
}

// swizzled XT index: row-stride 128, col4 XOR'd with (r>>2)&7 -> all k1 LDS
// accesses are <=2-way bank aliased (free on CDNA4).
__device__ __forceinline__ int xtidx(int r, int l) {
  return r * 128 + ((((l >> 2) ^ ((r >> 2) & 7)) << 2) | (l & 3));
}

// ---------------------------------------------------------------------------
// kA: blocks 0..63  : G[i][j] = Wk_i . Wk_j  (block = row i, 4 lanes per dot)
//     block 64      : w = Wk*bk, bb = bk.bk
//     blocks 65..320: M h-partials, register-tiled: block = (b, hc of 4, ds of 8
//                     64-wide). Per thread 4 i-rows x 4 d floats; Wk read along h
//                     as float4 (no scalar LDS reads -> no bank conflicts).
// grid 321 x 256
__global__ __launch_bounds__(256) void kA_pre(const float* __restrict__ Wk,
                                              const float* __restrict__ bk,
                                              const float* __restrict__ C,
                                              float* __restrict__ ws) {
  const int t = threadIdx.x;
  const int blk = blockIdx.x;

  if (blk < 64) {
    // G row blk
    const int j = t >> 2, kq = t & 3;
    const float4* a4 = (const float4*)(Wk + (size_t)blk * Hn) + kq * 32;
    const float4* b4 = (const float4*)(Wk + (size_t)j * Hn) + kq * 32;
    float s0 = 0.f, s1 = 0.f, s2 = 0.f, s3 = 0.f;
    #pragma unroll 8
    for (int h = 0; h < 32; ++h) {
      const float4 x = a4[h], y = b4[h];
      s0 += x.x * y.x; s1 += x.y * y.y; s2 += x.z * y.z; s3 += x.w * y.w;
    }
    float s = (s0 + s1) + (s2 + s3);
    s += __shfl_down(s, 2, 4);
    s += __shfl_down(s, 1, 4);
    if (kq == 0) ws[OFF_G + blk * 64 + j] = s;
    return;
  }
  if (blk == 64) {
    const int i = t >> 2, kq = t & 3;
    const float4* a4 = (const float4*)(Wk + (size_t)i * Hn) + kq * 32;
    const float4* b4 = (const float4*)bk + kq * 32;
    float s0 = 0.f, s1 = 0.f, s2 = 0.f, s3 = 0.f;
    #pragma unroll 8
    for (int h = 0; h < 32; ++h) {
      const float4 x = a4[h], y = b4[h];
      s0 += x.x * y.x; s1 += x.y * y.y; s2 += x.z * y.z; s3 += x.w * y.w;
    }
    float s = (s0 + s1) + (s2 + s3);
    s += __shfl_down(s, 2, 4);
    s += __shfl_down(s, 1, 4);
    if (kq == 0) ws[OFF_W + i] = s;
    if (t < 4) {
      const float4* b4b = (const float4*)bk + t * 32;
      float q0 = 0.f, q1 = 0.f, q2 = 0.f, q3 = 0.f;
      #pragma unroll 8
      for (int h = 0; h < 32; ++h) {
        const float4 y = b4b[h];
        q0 += y.x * y.x; q1 += y.y * y.y; q2 += y.z * y.z; q3 += y.w * y.w;
      }
      float q = (q0 + q1) + (q2 + q3);
      q += __shfl_down(q, 2, 4);
      q += __shfl_down(q, 1, 4);
      if (t == 0) ws[OFF_BB] = q;
    }
    return;
  }

  // ---- M / c1 partials (register-tiled) ----
  __shared__ __align__(16) float WkS[64][132];  // [i][h within 128-chunk]
  __shared__ __align__(16) float Cs[128][68];   // [h within chunk][d within 64-strip]
  __shared__ __align__(16) float bks[128];

  const int m = blk - 65;
  const int b = m >> 5;
  const int rem = m & 31;
  const int hc = rem >> 3;
  const int ds = rem & 7;
  const int h0 = hc * 128;
  const int d04 = ds * 16;                      // float4 offset of 64-wide strip

  const float4* Wk4 = (const float4*)Wk;
  const float4* C4b = (const float4*)(C + (size_t)b * Hn * Hn);
  #pragma unroll
  for (int p = 0; p < 8; ++p) {
    const int e = p * 256 + t;                  // 2048 float4 (64 x 32)
    const int r = e >> 5, c4 = e & 31;
    *(float4*)&WkS[r][c4 * 4] = Wk4[(size_t)r * 128 + (h0 >> 2) + c4];
  }
  #pragma unroll
  for (int p = 0; p < 8; ++p) {
    const int e = p * 256 + t;                  // 2048 float4 (128 x 16)
    const int r = e >> 4, c4 = e & 15;
    *(float4*)&Cs[r][c4 * 4] = C4b[(size_t)(h0 + r) * 128 + d04 + c4];
  }
  if (t < 32) *(float4*)&bks[t * 4] = ((const float4*)&bk[h0])[t];
  __syncthreads();

  const int ig = t >> 4;                        // i-group: rows ig*4 .. +3
  const int i4 = ig * 4;
  const int d4 = t & 15;                        // float4 col within strip
  float4 acc0 = make_float4(0.f, 0.f, 0.f, 0.f);
  float4 acc1 = make_float4(0.f, 0.f, 0.f, 0.f);
  float4 acc2 = make_float4(0.f, 0.f, 0.f, 0.f);
  float4 acc3 = make_float4(0.f, 0.f, 0.f, 0.f);
  float4 c1a  = make_float4(0.f, 0.f, 0.f, 0.f);

  #pragma unroll 4
  for (int h4 = 0; h4 < 128; h4 += 4) {
    const float4 w0 = *(const float4*)&WkS[i4 + 0][h4];
    const float4 w1 = *(const float4*)&WkS[i4 + 1][h4];
    const float4 w2 = *(const float4*)&WkS[i4 + 2][h4];
    const float4 w3 = *(const float4*)&WkS[i4 + 3][h4];
    const float4 c0 = *(const float4*)&Cs[h4 + 0][d4 * 4];
    const float4 c1 = *(const float4*)&Cs[h4 + 1][d4 * 4];
    const float4 c2 = *(const float4*)&Cs[h4 + 2][d4 * 4];
    const float4 c3 = *(const float4*)&Cs[h4 + 3][d4 * 4];

    acc0.x += w0.x*c0.x + w0.y*c1.x + w0.z*c2.x + w0.w*c3.x;
    acc0.y += w0.x*c0.y + w0.y*c1.y + w0.z*c2.y + w0.w*c3.y;
    acc0.z += w0.x*c0.z + w0.y*c1.z + w0.z*c2.z + w0.w*c3.z;
    acc0.w += w0.x*c0.w + w0.y*c1.w + w0.z*c2.w + w0.w*c3.w;
    acc1.x += w1.x*c0.x + w1.y*c1.x + w1.z*c2.x + w1.w*c3.x;
    acc1.y += w1.x*c0.y + w1.y*c1.y + w1.z*c2.y + w1.w*c3.y;
    acc1.z += w1.x*c0.z + w1.y*c1.z + w1.z*c2.z + w1.w*c3.z;
    acc1.w += w1.x*c0.w + w1.y*c1.w + w1.z*c2.w + w1.w*c3.w;
    acc2.x += w2.x*c0.x + w2.y*c1.x + w2.z*c2.x + w2.w*c3.x;
    acc2.y += w2.x*c0.y + w2.y*c1.y + w2.z*c2.y + w2.w*c3.y;
    acc2.z += w2.x*c0.z + w2.y*c1.z + w2.z*c2.z + w2.w*c3.z;
    acc2.w += w2.x*c0.w + w2.y*c1.w + w2.z*c2.w + w2.w*c3.w;
    acc3.x += w3.x*c0.x + w3.y*c1.x + w3.z*c2.x + w3.w*c3.x;
    acc3.y += w3.x*c0.y + w3.y*c1.y + w3.z*c2.y + w3.w*c3.y;
    acc3.z += w3.x*c0.z + w3.y*c1.z + w3.z*c2.z + w3.w*c3.z;
    acc3.w += w3.x*c0.w + w3.y*c1.w + w3.z*c2.w + w3.w*c3.w;

    if (ig == 0) {
      const float b0 = bks[h4 + 0], b1 = bks[h4 + 1];
      const float b2 = bks[h4 + 2], b3 = bks[h4 + 3];
      c1a.x += b0*c0.x + b1*c1.x + b2*c2.x + b3*c3.x;
      c1a.y += b0*c0.y + b1*c1.y + b2*c2.y + b3*c3.y;
      c1a.z += b0*c0.z + b1*c1.z + b2*c2.z + b3*c3.z;
      c1a.w += b0*c0.w + b1*c1.w + b2*c2.w + b3*c3.w;
    }
  }

  float4* MP4 = (float4*)(ws + OFF_MP);
  const size_t base = (size_t)(b * NHC + hc) * 64;
  MP4[(base + i4 + 0) * 128 + d04 + d4] = acc0;
  MP4[(base + i4 + 1) * 128 + d04 + d4] = acc1;
  MP4[(base + i4 + 2) * 128 + d04 + d4] = acc2;
  MP4[(base + i4 + 3) * 128 + d04 + d4] = acc3;
  if (ig == 0) {
    float4* c14 = (float4*)(ws + OFF_C1P);
    c14[(size_t)(b * NHC + hc) * 128 + d04 + d4] = c1a;
  }
}

// ---------------------------------------------------------------------------
// k1: per 128-row tile: row norms via x*G*x + 2x.w + bb (G from GLOBAL,
//     n2 reduced by shfl_xor butterfly), then A1/A2/u/sig partials.
// LDS ~34KB -> 4 blocks/CU. grid 512 (= 8 b x 64 seg) x 256
__global__ __launch_bounds__(256, 4) void k1_stats(const float* __restrict__ hs,
                                                   float* __restrict__ ws) {
  __shared__ __align__(16) float XTS[8192];   // swizzled [64][128], 32KB
  __shared__ __align__(16) float d1s[LT];
  __shared__ __align__(16) float d2s[LT];
  __shared__ __align__(16) float wsh[64];

  const int t = threadIdx.x;
  const int idx = blockIdx.x;
  const int b = idx >> 6;
  const int seg = idx & 63;

  if (t < 64) wsh[t] = ws[OFF_W + t];
  const float bb = ws[OFF_BB];

  // stage X transposed + swizzled
  {
    const float4* src = (const float4*)(hs + ((size_t)b * Ln + (size_t)seg * LT) * Rn);
    #pragma unroll
    for (int k = 0; k < 8; ++k) {
      int f = k * 256 + t;
      float4 v = src[f];
      int l = f >> 4, j0 = (f & 15) << 2;
      XTS[xtidx(j0 + 0, l)] = v.x;
      XTS[xtidx(j0 + 1, l)] = v.y;
      XTS[xtidx(j0 + 2, l)] = v.z;
      XTS[xtidx(j0 + 3, l)] = v.w;
    }
  }
  __syncthreads();

  // phase A: Y[i][l] = sum_k G[i][k]*X[k][l]; G streamed from global (L1/L2)
  {
    const int i0 = (t & 7) * 8;
    const int lc = t >> 3;              // col4 index
    const int la = lc * 4;
    const float* Gg = ws + OFF_G;
    float acc[8][4] = {};
    for (int k = 0; k < 64; ++k) {
      const float4 g0 = *(const float4*)(Gg + (size_t)k * 64 + i0);
      const float4 g1 = *(const float4*)(Gg + (size_t)k * 64 + i0 + 4);
      const float4 xv = *(const float4*)&XTS[k * 128 + ((lc ^ ((k >> 2) & 7)) << 2)];
      const float ga[8] = {g0.x, g0.y, g0.z, g0.w, g1.x, g1.y, g1.z, g1.w};
      const float xa[4] = {xv.x, xv.y, xv.z, xv.w};
      #pragma unroll
      for (int a = 0; a < 8; ++a)
        #pragma unroll
        for (int lv = 0; lv < 4; ++lv)
          acc[a][lv] += ga[a] * xa[lv];
    }
    // per-thread n2 partial over i-slice, then butterfly over the 8 slices
    float s[4];
    #pragma unroll
    for (int lv = 0; lv < 4; ++lv) {
      float v = 0.f;
      #pragma unroll
      for (int a = 0; a < 8; ++a)
        v += XTS[xtidx(i0 + a, la + lv)] * (acc[a][lv] + 2.0f * wsh[i0 + a]);
      s[lv] = v;
    }
    #pragma unroll
    for (int off = 1; off <= 4; off <<= 1) {
      #pragma unroll
      for (int lv = 0; lv < 4; ++lv) s[lv] += __shfl_xor(s[lv], off, 64);
    }
    if ((t & 7) == 0) {
      #pragma unroll
      for (int lv = 0; lv < 4; ++lv) {
        float n2 = fmaxf(bb + s[lv], 0.0f);
        const float d1 = 1.0f / fmaxf(sqrtf(n2), 1e-12f);
        d1s[la + lv] = d1;
        d2s[la + lv] = d1 * d1;
      }
    }
  }
  __syncthreads();

  float sg1 = 0.f, sg2 = 0.f;
  if (t < 64) {
    float a1 = d1s[t] + d1s[t + 64];
    float a2 = d2s[t] + d2s[t + 64];
    #pragma unroll
    for (int off = 32; off > 0; off >>= 1) {
      a1 += __shfl_down(a1, off, 64);
      a2 += __shfl_down(a2, off, 64);
    }
    sg1 = a1; sg2 = a2;
  }

  // phase B: A1/A2 4x4 per-thread accumulation over the tile
  const int rb = t >> 4;             // xi row-group
  const int rc = t & 15;             // xj row-group
  const int bi0 = rb * 4;
  const int bj0 = rc * 4;
  float A1a[4][4] = {}, A2a[4][4] = {};
  float u1a[4] = {0.f, 0.f, 0.f, 0.f}, u2a[4] = {0.f, 0.f, 0.f, 0.f};
  for (int l4 = 0; l4 < LT; l4 += 4) {
    const int c4 = l4 >> 2;
    const float4 q1 = *(const float4*)&d1s[l4];
    const float4 q2 = *(const float4*)&d2s[l4];
    const float d1v[4] = {q1.x, q1.y, q1.z, q1.w};
    const float d2v[4] = {q2.x, q2.y, q2.z, q2.w};
    float e1[4][4], e2[4][4], xj[4][4];
    const int swi = (c4 ^ (rb & 7)) << 2;
    const int swj = (c4 ^ (rc & 7)) << 2;
    #pragma unroll
    for (int a = 0; a < 4; ++a) {
      const float4 xv = *(const float4*)&XTS[(bi0 + a) * 128 + swi];
      const float xa[4] = {xv.x, xv.y, xv.z, xv.w};
      #pragma unroll
      for (int lv = 0; lv < 4; ++lv) {
        e1[a][lv] = d1v[lv] * xa[lv];
        e2[a][lv] = d2v[lv] * xa[lv];
      }
    }
    #pragma unroll
    for (int bq = 0; bq < 4; ++bq) {
      const float4 xv = *(const float4*)&XTS[(bj0 + bq) * 128 + swj];
      xj[bq][0] = xv.x; xj[bq][1] = xv.y; xj[bq][2] = xv.z; xj[bq][3] = xv.w;
    }
    #pragma unroll
    for (int a = 0; a < 4; ++a)
      #pragma unroll
      for (int bq = 0; bq < 4; ++bq) {
        float s1 = A1a[a][bq], s2 = A2a[a][bq];
        #pragma unroll
        for (int lv = 0; lv < 4; ++lv) {
          s1 += e1[a][lv] * xj[bq][lv];
          s2 += e2[a][lv] * xj[bq][lv];
        }
        A1a[a][bq] = s1; A2a[a][bq] = s2;
      }
    if (bj0 == 0) {
      #pragma unroll
      for (int a = 0; a < 4; ++a)
        #pragma unroll
        for (int lv = 0; lv < 4; ++lv) {
          u1a[a] += e1[a][lv];
          u2a[a] += e2[a][lv];
        }
    }
  }

  float* P = ws + OFF_STATS + (size_t)idx * PS;
  #pragma unroll
  for (int a = 0; a < 4; ++a)
    #pragma unroll
    for (int bq = 0; bq < 4; ++bq) {
      P[(bi0 + a) * 64 + bj0 + bq] = A1a[a][bq];
      P[4096 + (bi0 + a) * 64 + bj0 + bq] = A2a[a][bq];
    }
  if (bj0 == 0) {
    #pragma unroll
    for (int a = 0; a < 4; ++a) {
      P[8192 + bi0 + a] = u1a[a];
      P[8256 + bi0 + a] = u2a[a];
    }
  }
  if (t == 0) { P[8320] = sg1; P[8321] = sg2; }
}

// ---------------------------------------------------------------------------
// k1b: reduce 64 partials per batch -> A1R, A2R, U1R, U2R, SIG
// grid 256 (= b(8) x sel(2) x q(16)) x 256
__global__ __launch_bounds__(256) void k1b_reduce(float* __restrict__ ws) {
  const int t = threadIdx.x;
  const int blk = blockIdx.x;
  const int b = blk >> 5, sel = (blk >> 4) & 1, q = blk & 15;
  const float* SB = ws + OFF_STATS + (size_t)b * 64 * PS + (size_t)sel * 4096;
  float* dst = ws + (sel ? OFF_A2R : OFF_A1R) + (size_t)b * 4096;
  const int e = q * 256 + t;
  float s = 0.f;
  #pragma unroll 8
  for (int p = 0; p < 64; ++p) s += SB[(size_t)p * PS + e];
  dst[e] = s;
  if (sel == 0 && q == 0) {
    const float* UB = ws + OFF_STATS + (size_t)b * 64 * PS;
    if (t < 64) {
      float s2 = 0.f;
      #pragma unroll 8
      for (int p = 0; p < 64; ++p) s2 += UB[(size_t)p * PS + 8192 + t];
      ws[OFF_U1R + b * 64 + t] = s2;
    } else if (t < 128) {
      const int i = t - 64;
      float s2 = 0.f;
      #pragma unroll 8
      for (int p = 0; p < 64; ++p) s2 += UB[(size_t)p * PS + 8256 + i];
      ws[OFF_U2R + b * 64 + i] = s2;
    } else if (t == 128) {
      float s1 = 0.f, s2 = 0.f;
      for (int p = 0; p < 64; ++p) {
        s1 += UB[(size_t)p * PS + 8320];
        s2 += UB[(size_t)p * PS + 8321];
      }
      ws[OFF_SIG + b * 2] = s1;
      ws[OFF_SIG + b * 2 + 1] = s2;
    }
  }
}

// ---------------------------------------------------------------------------
// k2p: Td = A1 @ Wv - A2 @ M  (M = sum of 4 h-partials)
//      p1 = Wk^T u1, p2 = Wk^T u2, q1 = Wv^T u1, g = u2^T M
// grid 128 (= b(8) x ds(16, 32-wide)) x 256
__global__ __launch_bounds__(256) void k2p_td(const float* __restrict__ Wk,
                                              const float* __restrict__ Wv,
                                              float* __restrict__ ws) {
  __shared__ __align__(16) float A1s[64][66];
  __shared__ __align__(16) float A2s[64][66];
  __shared__ __align__(16) float Wvt[64][36];
  __shared__ __align__(16) float Mt[64][36];
  __shared__ __align__(16) float u1s[64];
  __shared__ __align__(16) float u2s[64];

  const int t = threadIdx.x;
  const int blk = blockIdx.x;
  const int b = blk >> 4;
  const int ds = blk & 15;
  const int d04 = ds * 8;

  const float4* A1R4 = (const float4*)(ws + OFF_A1R + (size_t)b * 4096);
  const float4* A2R4 = (const float4*)(ws + OFF_A2R + (size_t)b * 4096);
  #pragma unroll
  for (int p = 0; p < 4; ++p) {
    const int idx = p * 256 + t;
    const int r = idx >> 4, c0 = (idx & 15) * 4;
    *(float4*)&A1s[r][c0] = A1R4[idx];
    *(float4*)&A2s[r][c0] = A2R4[idx];
  }
  const float4* Wv4 = (const float4*)Wv;
  const float4* MP4 = (const float4*)(ws + OFF_MP);
  #pragma unroll
  for (int p = 0; p < 2; ++p) {
    const int idx = p * 256 + t;
    const int r = idx >> 3, c4 = idx & 7;
    *(float4*)&Wvt[r][c4 * 4] = Wv4[(size_t)r * 128 + d04 + c4];
    float4 m = MP4[((size_t)(b * NHC + 0) * 64 + r) * 128 + d04 + c4];
    #pragma unroll
    for (int q = 1; q < NHC; ++q) {
      const float4 mq = MP4[((size_t)(b * NHC + q) * 64 + r) * 128 + d04 + c4];
      m.x += mq.x; m.y += mq.y; m.z += mq.z; m.w += mq.w;
    }
    *(float4*)&Mt[r][c4 * 4] = m;
  }
  if (t < 16) {
    *(float4*)&u1s[t * 4] = *(const float4*)(ws + OFF_U1R + b * 64 + t * 4);
  } else if (t < 32) {
    const int i = t - 16;
    *(float4*)&u2s[i * 4] = *(const float4*)(ws + OFF_U2R + b * 64 + i * 4);
  }
  __syncthreads();

  const int ig = t >> 3;         // rows i = ig*2, ig*2+1
  const int tj4 = t & 7;
  float4 acc0 = make_float4(0.f, 0.f, 0.f, 0.f);
  float4 acc1 = make_float4(0.f, 0.f, 0.f, 0.f);
  #pragma unroll 8
  for (int j = 0; j < 64; ++j) {
    const float4 wv = *(const float4*)&Wvt[j][tj4 * 4];
    const float4 mv = *(const float4*)&Mt[j][tj4 * 4];
    const float a10 = A1s[ig * 2][j], a20 = A2s[ig * 2][j];
    const float a11 = A1s[ig * 2 + 1][j], a21 = A2s[ig * 2 + 1][j];
    acc0.x += a10 * wv.x - a20 * mv.x; acc0.y += a10 * wv.y - a20 * mv.y;
    acc0.z += a10 * wv.z - a20 * mv.z; acc0.w += a10 * wv.w - a20 * mv.w;
    acc1.x += a11 * wv.x - a21 * mv.x; acc1.y += a11 * wv.y - a21 * mv.y;
    acc1.z += a11 * wv.z - a21 * mv.z; acc1.w += a11 * wv.w - a21 * mv.w;
  }
  float4* Td4 = (float4*)(ws + OFF_TD + (size_t)b * 64 * Hn);
  Td4[(size_t)(ig * 2)     * 128 + d04 + tj4] = acc0;
  Td4[(size_t)(ig * 2 + 1) * 128 + d04 + tj4] = acc1;

  if (t < 32) {
    const int d = ds * 32 + t;
    float q1 = 0.f, g = 0.f;
    #pragma unroll 8
    for (int i = 0; i < 64; ++i) {
      q1 += u1s[i] * Wvt[i][t];
      g  += u2s[i] * Mt[i][t];
    }
    ws[OFF_Q1 + (size_t)b * Hn + d] = q1;
    ws[OFF_GV + (size_t)b * Hn + d] = g;
  } else if (t < 64) {
    const int h = ds * 32 + (t - 32);
    float p1 = 0.f, p2 = 0.f;
    #pragma unroll 8
    for (int i = 0; i < 64; ++i) {
      const float wv = Wk[(size_t)i * Hn + h];
      p1 += wv * u1s[i];
      p2 += wv * u2s[i];
    }
    ws[OFF_P1 + (size_t)b * Hn + h] = p1;
    ws[OFF_P2 + (size_t)b * Hn + h] = p2;
  }
}

// ---------------------------------------------------------------------------
// k4: out = C + Wk^T Td + (p1 + sig1*bk) (x) bv + bk (x) (q1 - g - sig2*c1) - p2 (x) c1
// grid 512 (= b(8) x hstrip(8, 64-wide) x dstrip(8, 64-wide)) x 256
__global__ __launch_bounds__(256) void k4_out(const float* __restrict__ C,
                                              const float* __restrict__ Wk,
                                              const float* __restrict__ bk,
                                              const float* __restrict__ bv,
                                              const float* __restrict__ ws,
                                              float* __restrict__ out) {
  __shared__ __align__(16) float Tds[64][68];
  __shared__ __align__(16) float Wks[64][68];
  __shared__ float phs[64], bks[64], p2s[64];
  __shared__ float bvs[64], terms[64], c1s[64];

  const int t = threadIdx.x;
  const int blk = blockIdx.x;
  const int b = blk >> 6;
  const int rem = blk & 63;
  const int hs0 = (rem >> 3) * 64;
  const int d04 = (rem & 7) * 16;               // float4 offset of 64-wide d strip
  const float sg1 = ws[OFF_SIG + b * 2];
  const float sg2 = ws[OFF_SIG + b * 2 + 1];

  const float4* TdG4 = (const float4*)(ws + OFF_TD + (size_t)b * 64 * Hn);
  const float4* Wk4 = (const float4*)Wk;
  #pragma unroll
  for (int p = 0; p < 4; ++p) {
    const int e = p * 256 + t;                  // 1024 float4 (64 x 16)
    const int r = e >> 4, c4 = e & 15;
    *(float4*)&Tds[r][c4 * 4] = TdG4[(size_t)r * 128 + d04 + c4];
    *(float4*)&Wks[r][c4 * 4] = Wk4[(size_t)r * 128 + (hs0 >> 2) + c4];
  }
  if (t < 64) {
    const int h = hs0 + t;
    const float bkv = bk[h];
    bks[t] = bkv;
    phs[t] = ws[OFF_P1 + (size_t)b * Hn + h] + sg1 * bkv;
    p2s[t] = ws[OFF_P2 + (size_t)b * Hn + h];
  } else if (t < 128) {
    const int dd = t - 64;
    const int d = d04 * 4 + dd;
    float c1 = 0.f;
    #pragma unroll
    for (int q = 0; q < NHC; ++q)
      c1 += ws[OFF_C1P + (size_t)(b * NHC + q) * Hn + d];
    c1s[dd] = c1;
    bvs[dd] = bv[d];
    terms[dd] = ws[OFF_Q1 + (size_t)b * Hn + d] - ws[OFF_GV + (size_t)b * Hn + d] - sg2 * c1;
  }
  __syncthreads();

  const int ti = t >> 4;   // rows hh = ti*4 .. +4
  const int tj4 = t & 15;  // d float4 within strip
  float4 acc[4];
  #pragma unroll
  for (int a = 0; a < 4; ++a) acc[a] = make_float4(0.f, 0.f, 0.f, 0.f);
  for (int j = 0; j < 64; ++j) {
    const float4 td4 = *(const float4*)&Tds[j][tj4 * 4];
    #pragma unroll
    for (int a = 0; a < 4; ++a) {
      const float wv = Wks[j][ti * 4 + a];
      acc[a].x += wv * td4.x; acc[a].y += wv * td4.y;
      acc[a].z += wv * td4.z; acc[a].w += wv * td4.w;
    }
  }

  const float4* C4b = (const float4*)(C + (size_t)b * Hn * Hn);
  float4* out4 = (float4*)(out + (size_t)b * Hn * Hn);
  const float4 bv4 = *(const float4*)&bvs[tj4 * 4];
  const float4 tm4 = *(const float4*)&terms[tj4 * 4];
  const float4 c14 = *(const float4*)&c1s[tj4 * 4];
  #pragma unroll
  for (int a = 0; a < 4; ++a) {
    const int hh = ti * 4 + a;
    const int h = hs0 + hh;
    const float4 c = C4b[(size_t)h * 128 + d04 + tj4];
    const float ph = phs[hh], bkh = bks[hh], p2h = p2s[hh];
    float4 o;
    o.x = c.x + acc[a].x + ph * bv4.x + bkh * tm4.x - p2h * c14.x;
    o.y = c.y + acc[a].y + ph * bv4.y + bkh * tm4.y - p2h * c14.y;
    o.z = c.z + acc[a].z + ph * bv4.z + bkh * tm4.z - p2h * c14.z;
    o.w = c.w + acc[a].w + ph * bv4.w + bkh * tm4.w - p2h * c14.w;
    out4[(size_t)h * 128 + d04 + tj4] = o;
  }
}

// ---------------------------------------------------------------------------
extern "C" void kernel_launch(void* const* d_in, const int* in_sizes, int n_in,
                              void* d_out, int out_size, void* d_ws, size_t ws_size,
                              hipStream_t stream) {
  const float* hs = (const float*)d_in[0];
  const float* C  = (const float*)d_in[1];
  const float* Wk = (const float*)d_in[2];
  const float* bk = (const float*)d_in[3];
  const float* Wv = (const float*)d_in[4];
  const float* bv = (const float*)d_in[5];
  float* out = (float*)d_out;
  float* ws = (float*)d_ws;
  (void)in_sizes; (void)n_in; (void)out_size; (void)ws_size;

  hipLaunchKernelGGL(kA_pre,     dim3(321), dim3(256), 0, stream, Wk, bk, C, ws);
  hipLaunchKernelGGL(k1_stats,   dim3(512), dim3(256), 0, stream, hs, ws);
  hipLaunchKernelGGL(k1b_reduce, dim3(256), dim3(256), 0, stream, ws);
  hipLaunchKernelGGL(k2p_td,     dim3(128), dim3(256), 0, stream, Wk, Wv, ws);
  hipLaunchKernelGGL(k4_out,     dim3(512), dim3(256), 0, stream, C, Wk, bk, bv, ws, out);
}

// Round 8
// 70.196 us; speedup vs baseline: 1.3345x; 1.1584x over previous
//
#include <hip/hip_runtime.h>
#include <hip/hip_bf16.h>
#include <math.h>

namespace {
constexpr int Bn = 8;
constexpr int Ln = 8192;
constexpr int Rn = 64;
constexpr int Hn = 512;
constexpr int LT = 128;
constexpr int NSEG = Ln / LT;            // 64 segments per batch
constexpr int NK1 = Bn * NSEG;           // 512 k1 blocks
constexpr int NHC = 4;                   // M h-chunks (128 h each)

// workspace float offsets
constexpr size_t PS        = 8352;       // per-k1-block partial stride
constexpr size_t OFF_G     = 0;                                   // 64x64
constexpr size_t OFF_W     = 4096;                                // 64
constexpr size_t OFF_BB    = 4160;                                // 1 (+pad)
constexpr size_t OFF_STATS = 4224;                                // NK1 * PS
constexpr size_t OFF_A1R   = OFF_STATS + (size_t)NK1 * PS;        // B*4096
constexpr size_t OFF_A2R   = OFF_A1R + (size_t)Bn * 4096;         // B*4096
constexpr size_t OFF_U1R   = OFF_A2R + (size_t)Bn * 4096;         // B*64
constexpr size_t OFF_U2R   = OFF_U1R + (size_t)Bn * 64;           // B*64
constexpr size_t OFF_SIG   = OFF_U2R + (size_t)Bn * 64;           // B*2 (pad 64)
constexpr size_t OFF_MP    = OFF_SIG + 64;                        // B*NHC*64*H (M h-partials)
constexpr size_t OFF_C1P   = OFF_MP + (size_t)Bn * NHC * 64 * Hn; // B*NHC*H
constexpr size_t OFF_TD    = OFF_C1P + (size_t)Bn * NHC * Hn;     // B*64*H
constexpr size_t OFF_P1    = OFF_TD + (size_t)Bn * 64 * Hn;       // B*H
constexpr size_t OFF_P2    = OFF_P1 + (size_t)Bn * Hn;            // B*H
constexpr size_t OFF_Q1    = OFF_P2 + (size_t)Bn * Hn;            // B*H
constexpr size_t OFF_GV    = OFF_Q1 + (size_t)Bn * Hn;            // B*H     (g = u2^T M)
}

using short8v = __attribute__((ext_vector_type(8))) short;
using f32x4v  = __attribute__((ext_vector_type(4))) float;

// bf16 [64 r][128 l] array, 8-element (16B) granules XOR-swizzled by row:
// element index for (r,l); all 16B frag reads stay granule-contiguous.
__device__ __forceinline__ int bidx(int r, int l) {
  return (r << 7) + ((((l >> 3) ^ (r & 7)) << 3) | (l & 7));
}
__device__ __forceinline__ short tobf(float x) {
  __hip_bfloat16 h = __float2bfloat16(x);
  return __builtin_bit_cast(short, h);
}
__device__ __forceinline__ float frombf(short s) {
  union { unsigned int u; float f; } c;
  c.u = ((unsigned int)(unsigned short)s) << 16;
  return c.f;
}

// ---------------------------------------------------------------------------
// kA: blocks 0..63  : G[i][j] = Wk_i . Wk_j ; block 64: w = Wk*bk, bb = bk.bk
//     blocks 65..320: M h-partials, register-tiled (unchanged from R7)
// grid 321 x 256
__global__ __launch_bounds__(256) void kA_pre(const float* __restrict__ Wk,
                                              const float* __restrict__ bk,
                                              const float* __restrict__ C,
                                              float* __restrict__ ws) {
  const int t = threadIdx.x;
  const int blk = blockIdx.x;

  if (blk < 64) {
    const int j = t >> 2, kq = t & 3;
    const float4* a4 = (const float4*)(Wk + (size_t)blk * Hn) + kq * 32;
    const float4* b4 = (const float4*)(Wk + (size_t)j * Hn) + kq * 32;
    float s0 = 0.f, s1 = 0.f, s2 = 0.f, s3 = 0.f;
    #pragma unroll 8
    for (int h = 0; h < 32; ++h) {
      const float4 x = a4[h], y = b4[h];
      s0 += x.x * y.x; s1 += x.y * y.y; s2 += x.z * y.z; s3 += x.w * y.w;
    }
    float s = (s0 + s1) + (s2 + s3);
    s += __shfl_down(s, 2, 4);
    s += __shfl_down(s, 1, 4);
    if (kq == 0) ws[OFF_G + blk * 64 + j] = s;
    return;
  }
  if (blk == 64) {
    const int i = t >> 2, kq = t & 3;
    const float4* a4 = (const float4*)(Wk + (size_t)i * Hn) + kq * 32;
    const float4* b4 = (const float4*)bk + kq * 32;
    float s0 = 0.f, s1 = 0.f, s2 = 0.f, s3 = 0.f;
    #pragma unroll 8
    for (int h = 0; h < 32; ++h) {
      const float4 x = a4[h], y = b4[h];
      s0 += x.x * y.x; s1 += x.y * y.y; s2 += x.z * y.z; s3 += x.w * y.w;
    }
    float s = (s0 + s1) + (s2 + s3);
    s += __shfl_down(s, 2, 4);
    s += __shfl_down(s, 1, 4);
    if (kq == 0) ws[OFF_W + i] = s;
    if (t < 4) {
      const float4* b4b = (const float4*)bk + t * 32;
      float q0 = 0.f, q1 = 0.f, q2 = 0.f, q3 = 0.f;
      #pragma unroll 8
      for (int h = 0; h < 32; ++h) {
        const float4 y = b4b[h];
        q0 += y.x * y.x; q1 += y.y * y.y; q2 += y.z * y.z; q3 += y.w * y.w;
      }
      float q = (q0 + q1) + (q2 + q3);
      q += __shfl_down(q, 2, 4);
      q += __shfl_down(q, 1, 4);
      if (t == 0) ws[OFF_BB] = q;
    }
    return;
  }

  // ---- M / c1 partials (register-tiled) ----
  __shared__ __align__(16) float WkS[64][132];
  __shared__ __align__(16) float Cs[128][68];
  __shared__ __align__(16) float bks[128];

  const int m = blk - 65;
  const int b = m >> 5;
  const int rem = m & 31;
  const int hc = rem >> 3;
  const int ds = rem & 7;
  const int h0 = hc * 128;
  const int d04 = ds * 16;

  const float4* Wk4 = (const float4*)Wk;
  const float4* C4b = (const float4*)(C + (size_t)b * Hn * Hn);
  #pragma unroll
  for (int p = 0; p < 8; ++p) {
    const int e = p * 256 + t;
    const int r = e >> 5, c4 = e & 31;
    *(float4*)&WkS[r][c4 * 4] = Wk4[(size_t)r * 128 + (h0 >> 2) + c4];
  }
  #pragma unroll
  for (int p = 0; p < 8; ++p) {
    const int e = p * 256 + t;
    const int r = e >> 4, c4 = e & 15;
    *(float4*)&Cs[r][c4 * 4] = C4b[(size_t)(h0 + r) * 128 + d04 + c4];
  }
  if (t < 32) *(float4*)&bks[t * 4] = ((const float4*)&bk[h0])[t];
  __syncthreads();

  const int ig = t >> 4;
  const int i4 = ig * 4;
  const int d4 = t & 15;
  float4 acc0 = make_float4(0.f, 0.f, 0.f, 0.f);
  float4 acc1 = make_float4(0.f, 0.f, 0.f, 0.f);
  float4 acc2 = make_float4(0.f, 0.f, 0.f, 0.f);
  float4 acc3 = make_float4(0.f, 0.f, 0.f, 0.f);
  float4 c1a  = make_float4(0.f, 0.f, 0.f, 0.f);

  #pragma unroll 4
  for (int h4 = 0; h4 < 128; h4 += 4) {
    const float4 w0 = *(const float4*)&WkS[i4 + 0][h4];
    const float4 w1 = *(const float4*)&WkS[i4 + 1][h4];
    const float4 w2 = *(const float4*)&WkS[i4 + 2][h4];
    const float4 w3 = *(const float4*)&WkS[i4 + 3][h4];
    const float4 c0 = *(const float4*)&Cs[h4 + 0][d4 * 4];
    const float4 c1 = *(const float4*)&Cs[h4 + 1][d4 * 4];
    const float4 c2 = *(const float4*)&Cs[h4 + 2][d4 * 4];
    const float4 c3 = *(const float4*)&Cs[h4 + 3][d4 * 4];

    acc0.x += w0.x*c0.x + w0.y*c1.x + w0.z*c2.x + w0.w*c3.x;
    acc0.y += w0.x*c0.y + w0.y*c1.y + w0.z*c2.y + w0.w*c3.y;
    acc0.z += w0.x*c0.z + w0.y*c1.z + w0.z*c2.z + w0.w*c3.z;
    acc0.w += w0.x*c0.w + w0.y*c1.w + w0.z*c2.w + w0.w*c3.w;
    acc1.x += w1.x*c0.x + w1.y*c1.x + w1.z*c2.x + w1.w*c3.x;
    acc1.y += w1.x*c0.y + w1.y*c1.y + w1.z*c2.y + w1.w*c3.y;
    acc1.z += w1.x*c0.z + w1.y*c1.z + w1.z*c2.z + w1.w*c3.z;
    acc1.w += w1.x*c0.w + w1.y*c1.w + w1.z*c2.w + w1.w*c3.w;
    acc2.x += w2.x*c0.x + w2.y*c1.x + w2.z*c2.x + w2.w*c3.x;
    acc2.y += w2.x*c0.y + w2.y*c1.y + w2.z*c2.y + w2.w*c3.y;
    acc2.z += w2.x*c0.z + w2.y*c1.z + w2.z*c2.z + w2.w*c3.z;
    acc2.w += w2.x*c0.w + w2.y*c1.w + w2.z*c2.w + w2.w*c3.w;
    acc3.x += w3.x*c0.x + w3.y*c1.x + w3.z*c2.x + w3.w*c3.x;
    acc3.y += w3.x*c0.y + w3.y*c1.y + w3.z*c2.y + w3.w*c3.y;
    acc3.z += w3.x*c0.z + w3.y*c1.z + w3.z*c2.z + w3.w*c3.z;
    acc3.w += w3.x*c0.w + w3.y*c1.w + w3.z*c2.w + w3.w*c3.w;

    if (ig == 0) {
      const float b0 = bks[h4 + 0], b1 = bks[h4 + 1];
      const float b2 = bks[h4 + 2], b3 = bks[h4 + 3];
      c1a.x += b0*c0.x + b1*c1.x + b2*c2.x + b3*c3.x;
      c1a.y += b0*c0.y + b1*c1.y + b2*c2.y + b3*c3.y;
      c1a.z += b0*c0.z + b1*c1.z + b2*c2.z + b3*c3.z;
      c1a.w += b0*c0.w + b1*c1.w + b2*c2.w + b3*c3.w;
    }
  }

  float4* MP4 = (float4*)(ws + OFF_MP);
  const size_t base = (size_t)(b * NHC + hc) * 64;
  MP4[(base + i4 + 0) * 128 + d04 + d4] = acc0;
  MP4[(base + i4 + 1) * 128 + d04 + d4] = acc1;
  MP4[(base + i4 + 2) * 128 + d04 + d4] = acc2;
  MP4[(base + i4 + 3) * 128 + d04 + d4] = acc3;
  if (ig == 0) {
    float4* c14 = (float4*)(ws + OFF_C1P);
    c14[(size_t)(b * NHC + hc) * 128 + d04 + d4] = c1a;
  }
}

// ---------------------------------------------------------------------------
// k1: per 128-row tile.
//   stage X as bf16 (swizzled [64][128]) -> phase A fp32 (n2 via G from global)
//   -> build F = sqrt(d)*X, E = d*X (bf16) -> MFMA: A1 = F^T F, A2 = E^T E.
//   u1/u2 in fp32 during the build; sig via shuffle.
// grid 512 x 256, 3 blocks/CU
__global__ __launch_bounds__(256, 3) void k1_stats(const float* __restrict__ hs,
                                                   float* __restrict__ ws) {
  __shared__ __align__(16) short XB[8192];   // bf16 X^T  [r=64][l=128], swizzled
  __shared__ __align__(16) short FB[8192];   // bf16 sqrt(d)*x
  __shared__ __align__(16) short EB[8192];   // bf16 d*x
  __shared__ __align__(16) float d1s[LT];
  __shared__ __align__(16) float dhs[LT];
  __shared__ __align__(16) float wsh[64];

  const int t = threadIdx.x;
  const int idx = blockIdx.x;
  const int b = idx >> 6;
  const int seg = idx & 63;

  if (t < 64) wsh[t] = ws[OFF_W + t];
  const float bb = ws[OFF_BB];

  // stage X transposed -> bf16 swizzled
  {
    const float4* src = (const float4*)(hs + ((size_t)b * Ln + (size_t)seg * LT) * Rn);
    #pragma unroll
    for (int k = 0; k < 8; ++k) {
      const int f = k * 256 + t;
      const float4 v = src[f];
      const int l = f >> 4, j0 = (f & 15) << 2;
      XB[bidx(j0 + 0, l)] = tobf(v.x);
      XB[bidx(j0 + 1, l)] = tobf(v.y);
      XB[bidx(j0 + 2, l)] = tobf(v.z);
      XB[bidx(j0 + 3, l)] = tobf(v.w);
    }
  }
  __syncthreads();

  // phase A: n2_l = x G x^T + 2 x.w + bb ; G streamed from global (L2)
  {
    const int i0 = (t & 7) * 8;
    const int la = (t >> 3) * 4;
    const float* Gg = ws + OFF_G;
    float acc[8][4] = {};
    for (int k = 0; k < 64; ++k) {
      const float4 g0 = *(const float4*)(Gg + (size_t)k * 64 + i0);
      const float4 g1 = *(const float4*)(Gg + (size_t)k * 64 + i0 + 4);
      const ushort4 xu = *(const ushort4*)&XB[bidx(k, la)];
      const float ga[8] = {g0.x, g0.y, g0.z, g0.w, g1.x, g1.y, g1.z, g1.w};
      const float xa[4] = {frombf((short)xu.x), frombf((short)xu.y),
                           frombf((short)xu.z), frombf((short)xu.w)};
      #pragma unroll
      for (int a = 0; a < 8; ++a)
        #pragma unroll
        for (int lv = 0; lv < 4; ++lv)
          acc[a][lv] += ga[a] * xa[lv];
    }
    float s[4];
    #pragma unroll
    for (int lv = 0; lv < 4; ++lv) {
      float v = 0.f;
      #pragma unroll
      for (int a = 0; a < 8; ++a)
        v += frombf(XB[bidx(i0 + a, la + lv)]) * (acc[a][lv] + 2.0f * wsh[i0 + a]);
      s[lv] = v;
    }
    #pragma unroll
    for (int off = 1; off <= 4; off <<= 1) {
      #pragma unroll
      for (int lv = 0; lv < 4; ++lv) s[lv] += __shfl_xor(s[lv], off, 64);
    }
    if ((t & 7) == 0) {
      #pragma unroll
      for (int lv = 0; lv < 4; ++lv) {
        const float n2 = fmaxf(bb + s[lv], 0.0f);
        const float d1 = 1.0f / fmaxf(sqrtf(n2), 1e-12f);
        d1s[la + lv] = d1;
        dhs[la + lv] = sqrtf(d1);
      }
    }
  }
  __syncthreads();

  float sg1 = 0.f, sg2 = 0.f;
  if (t < 64) {
    const float da = d1s[t], db = d1s[t + 64];
    float a1 = da + db;
    float a2 = da * da + db * db;
    #pragma unroll
    for (int off = 32; off > 0; off >>= 1) {
      a1 += __shfl_down(a1, off, 64);
      a2 += __shfl_down(a2, off, 64);
    }
    sg1 = a1; sg2 = a2;
  }

  float* P = ws + OFF_STATS + (size_t)idx * PS;

  // build F, E (bf16) + u1/u2 partials: thread -> (row r = t>>2, 32 l's)
  {
    const int r = t >> 2;
    const int lq = (t & 3) * 32;
    float u1p = 0.f, u2p = 0.f;
    #pragma unroll
    for (int g = 0; g < 4; ++g) {
      const int l0 = lq + g * 8;
      const ushort4* px = (const ushort4*)&XB[bidx(r, l0)];
      const ushort4 xlo = px[0], xhi = px[1];
      const float xs[8] = {frombf((short)xlo.x), frombf((short)xlo.y),
                           frombf((short)xlo.z), frombf((short)xlo.w),
                           frombf((short)xhi.x), frombf((short)xhi.y),
                           frombf((short)xhi.z), frombf((short)xhi.w)};
      short8v ev, fv;
      #pragma unroll
      for (int e = 0; e < 8; ++e) {
        const float d = d1s[l0 + e];
        const float dh = dhs[l0 + e];
        const float evf = d * xs[e];
        ev[e] = tobf(evf);
        fv[e] = tobf(dh * xs[e]);
        u1p += evf;
        u2p += d * evf;
      }
      *(short8v*)&EB[bidx(r, l0)] = ev;
      *(short8v*)&FB[bidx(r, l0)] = fv;
    }
    u1p += __shfl_down(u1p, 2, 4); u1p += __shfl_down(u1p, 1, 4);
    u2p += __shfl_down(u2p, 2, 4); u2p += __shfl_down(u2p, 1, 4);
    if ((t & 3) == 0) {
      P[8192 + r] = u1p;
      P[8256 + r] = u2p;
    }
  }
  __syncthreads();

  // MFMA: A1 = F^T F (to P+0), A2 = E^T E (to P+4096). 64x64, K=128.
  {
    const int lane = t & 63;
    const int w = t >> 6;              // wave -> i-rows 16w..16w+15
    const int lo = lane & 15;
    const int hi = lane >> 4;          // k-group
    #pragma unroll
    for (int mat = 0; mat < 2; ++mat) {
      const short* S = mat ? EB : FB;
      float* D = P + (mat ? 4096 : 0);
      short8v a[4];
      const int ra = w * 16 + lo;
      #pragma unroll
      for (int kc = 0; kc < 4; ++kc)
        a[kc] = *(const short8v*)&S[bidx(ra, kc * 32 + hi * 8)];
      #pragma unroll
      for (int jt = 0; jt < 4; ++jt) {
        f32x4v acc = {0.f, 0.f, 0.f, 0.f};
        const int rb = jt * 16 + lo;
        #pragma unroll
        for (int kc = 0; kc < 4; ++kc) {
          const short8v bfrag = *(const short8v*)&S[bidx(rb, kc * 32 + hi * 8)];
          acc = __builtin_amdgcn_mfma_f32_16x16x32_bf16(a[kc], bfrag, acc, 0, 0, 0);
        }
        #pragma unroll
        for (int reg = 0; reg < 4; ++reg)
          D[(w * 16 + hi * 4 + reg) * 64 + jt * 16 + lo] = acc[reg];
      }
    }
  }

  if (t == 0) { P[8320] = sg1; P[8321] = sg2; }
}

// ---------------------------------------------------------------------------
// k1b: reduce 64 partials per batch -> A1R, A2R, U1R, U2R, SIG
// grid 256 (= b(8) x sel(2) x q(16)) x 256
__global__ __launch_bounds__(256) void k1b_reduce(float* __restrict__ ws) {
  const int t = threadIdx.x;
  const int blk = blockIdx.x;
  const int b = blk >> 5, sel = (blk >> 4) & 1, q = blk & 15;
  const float* SB = ws + OFF_STATS + (size_t)b * 64 * PS + (size_t)sel * 4096;
  float* dst = ws + (sel ? OFF_A2R : OFF_A1R) + (size_t)b * 4096;
  const int e = q * 256 + t;
  float s = 0.f;
  #pragma unroll 8
  for (int p = 0; p < 64; ++p) s += SB[(size_t)p * PS + e];
  dst[e] = s;
  if (sel == 0 && q == 0) {
    const float* UB = ws + OFF_STATS + (size_t)b * 64 * PS;
    if (t < 64) {
      float s2 = 0.f;
      #pragma unroll 8
      for (int p = 0; p < 64; ++p) s2 += UB[(size_t)p * PS + 8192 + t];
      ws[OFF_U1R + b * 64 + t] = s2;
    } else if (t < 128) {
      const int i = t - 64;
      float s2 = 0.f;
      #pragma unroll 8
      for (int p = 0; p < 64; ++p) s2 += UB[(size_t)p * PS + 8256 + i];
      ws[OFF_U2R + b * 64 + i] = s2;
    } else if (t == 128) {
      float s1 = 0.f, s2 = 0.f;
      for (int p = 0; p < 64; ++p) {
        s1 += UB[(size_t)p * PS + 8320];
        s2 += UB[(size_t)p * PS + 8321];
      }
      ws[OFF_SIG + b * 2] = s1;
      ws[OFF_SIG + b * 2 + 1] = s2;
    }
  }
}

// ---------------------------------------------------------------------------
// k2p: Td = A1 @ Wv - A2 @ M  (M = sum of 4 h-partials)
//      p1 = Wk^T u1, p2 = Wk^T u2, q1 = Wv^T u1, g = u2^T M
// grid 128 (= b(8) x ds(16, 32-wide)) x 256
__global__ __launch_bounds__(256) void k2p_td(const float* __restrict__ Wk,
                                              const float* __restrict__ Wv,
                                              float* __restrict__ ws) {
  __shared__ __align__(16) float A1s[64][66];
  __shared__ __align__(16) float A2s[64][66];
  __shared__ __align__(16) float Wvt[64][36];
  __shared__ __align__(16) float Mt[64][36];
  __shared__ __align__(16) float u1s[64];
  __shared__ __align__(16) float u2s[64];

  const int t = threadIdx.x;
  const int blk = blockIdx.x;
  const int b = blk >> 4;
  const int ds = blk & 15;
  const int d04 = ds * 8;

  const float4* A1R4 = (const float4*)(ws + OFF_A1R + (size_t)b * 4096);
  const float4* A2R4 = (const float4*)(ws + OFF_A2R + (size_t)b * 4096);
  #pragma unroll
  for (int p = 0; p < 4; ++p) {
    const int idx = p * 256 + t;
    const int r = idx >> 4, c0 = (idx & 15) * 4;
    *(float4*)&A1s[r][c0] = A1R4[idx];
    *(float4*)&A2s[r][c0] = A2R4[idx];
  }
  const float4* Wv4 = (const float4*)Wv;
  const float4* MP4 = (const float4*)(ws + OFF_MP);
  #pragma unroll
  for (int p = 0; p < 2; ++p) {
    const int idx = p * 256 + t;
    const int r = idx >> 3, c4 = idx & 7;
    *(float4*)&Wvt[r][c4 * 4] = Wv4[(size_t)r * 128 + d04 + c4];
    float4 m = MP4[((size_t)(b * NHC + 0) * 64 + r) * 128 + d04 + c4];
    #pragma unroll
    for (int q = 1; q < NHC; ++q) {
      const float4 mq = MP4[((size_t)(b * NHC + q) * 64 + r) * 128 + d04 + c4];
      m.x += mq.x; m.y += mq.y; m.z += mq.z; m.w += mq.w;
    }
    *(float4*)&Mt[r][c4 * 4] = m;
  }
  if (t < 16) {
    *(float4*)&u1s[t * 4] = *(const float4*)(ws + OFF_U1R + b * 64 + t * 4);
  } else if (t < 32) {
    const int i = t - 16;
    *(float4*)&u2s[i * 4] = *(const float4*)(ws + OFF_U2R + b * 64 + i * 4);
  }
  __syncthreads();

  const int ig = t >> 3;
  const int tj4 = t & 7;
  float4 acc0 = make_float4(0.f, 0.f, 0.f, 0.f);
  float4 acc1 = make_float4(0.f, 0.f, 0.f, 0.f);
  #pragma unroll 8
  for (int j = 0; j < 64; ++j) {
    const float4 wv = *(const float4*)&Wvt[j][tj4 * 4];
    const float4 mv = *(const float4*)&Mt[j][tj4 * 4];
    const float a10 = A1s[ig * 2][j], a20 = A2s[ig * 2][j];
    const float a11 = A1s[ig * 2 + 1][j], a21 = A2s[ig * 2 + 1][j];
    acc0.x += a10 * wv.x - a20 * mv.x; acc0.y += a10 * wv.y - a20 * mv.y;
    acc0.z += a10 * wv.z - a20 * mv.z; acc0.w += a10 * wv.w - a20 * mv.w;
    acc1.x += a11 * wv.x - a21 * mv.x; acc1.y += a11 * wv.y - a21 * mv.y;
    acc1.z += a11 * wv.z - a21 * mv.z; acc1.w += a11 * wv.w - a21 * mv.w;
  }
  float4* Td4 = (float4*)(ws + OFF_TD + (size_t)b * 64 * Hn);
  Td4[(size_t)(ig * 2)     * 128 + d04 + tj4] = acc0;
  Td4[(size_t)(ig * 2 + 1) * 128 + d04 + tj4] = acc1;

  if (t < 32) {
    const int d = ds * 32 + t;
    float q1 = 0.f, g = 0.f;
    #pragma unroll 8
    for (int i = 0; i < 64; ++i) {
      q1 += u1s[i] * Wvt[i][t];
      g  += u2s[i] * Mt[i][t];
    }
    ws[OFF_Q1 + (size_t)b * Hn + d] = q1;
    ws[OFF_GV + (size_t)b * Hn + d] = g;
  } else if (t < 64) {
    const int h = ds * 32 + (t - 32);
    float p1 = 0.f, p2 = 0.f;
    #pragma unroll 8
    for (int i = 0; i < 64; ++i) {
      const float wv = Wk[(size_t)i * Hn + h];
      p1 += wv * u1s[i];
      p2 += wv * u2s[i];
    }
    ws[OFF_P1 + (size_t)b * Hn + h] = p1;
    ws[OFF_P2 + (size_t)b * Hn + h] = p2;
  }
}

// ---------------------------------------------------------------------------
// k4: out = C + Wk^T Td + (p1 + sig1*bk) (x) bv + bk (x) (q1 - g - sig2*c1) - p2 (x) c1
// grid 512 (= b(8) x hstrip(8, 64-wide) x dstrip(8, 64-wide)) x 256
__global__ __launch_bounds__(256) void k4_out(const float* __restrict__ C,
                                              const float* __restrict__ Wk,
                                              const float* __restrict__ bk,
                                              const float* __restrict__ bv,
                                              const float* __restrict__ ws,
                                              float* __restrict__ out) {
  __shared__ __align__(16) float Tds[64][68];
  __shared__ __align__(16) float Wks[64][68];
  __shared__ float phs[64], bks[64], p2s[64];
  __shared__ float bvs[64], terms[64], c1s[64];

  const int t = threadIdx.x;
  const int blk = blockIdx.x;
  const int b = blk >> 6;
  const int rem = blk & 63;
  const int hs0 = (rem >> 3) * 64;
  const int d04 = (rem & 7) * 16;
  const float sg1 = ws[OFF_SIG + b * 2];
  const float sg2 = ws[OFF_SIG + b * 2 + 1];

  const float4* TdG4 = (const float4*)(ws + OFF_TD + (size_t)b * 64 * Hn);
  const float4* Wk4 = (const float4*)Wk;
  #pragma unroll
  for (int p = 0; p < 4; ++p) {
    const int e = p * 256 + t;
    const int r = e >> 4, c4 = e & 15;
    *(float4*)&Tds[r][c4 * 4] = TdG4[(size_t)r * 128 + d04 + c4];
    *(float4*)&Wks[r][c4 * 4] = Wk4[(size_t)r * 128 + (hs0 >> 2) + c4];
  }
  if (t < 64) {
    const int h = hs0 + t;
    const float bkv = bk[h];
    bks[t] = bkv;
    phs[t] = ws[OFF_P1 + (size_t)b * Hn + h] + sg1 * bkv;
    p2s[t] = ws[OFF_P2 + (size_t)b * Hn + h];
  } else if (t < 128) {
    const int dd = t - 64;
    const int d = d04 * 4 + dd;
    float c1 = 0.f;
    #pragma unroll
    for (int q = 0; q < NHC; ++q)
      c1 += ws[OFF_C1P + (size_t)(b * NHC + q) * Hn + d];
    c1s[dd] = c1;
    bvs[dd] = bv[d];
    terms[dd] = ws[OFF_Q1 + (size_t)b * Hn + d] - ws[OFF_GV + (size_t)b * Hn + d] - sg2 * c1;
  }
  __syncthreads();

  const int ti = t >> 4;
  const int tj4 = t & 15;
  float4 acc[4];
  #pragma unroll
  for (int a = 0; a < 4; ++a) acc[a] = make_float4(0.f, 0.f, 0.f, 0.f);
  for (int j = 0; j < 64; ++j) {
    const float4 td4 = *(const float4*)&Tds[j][tj4 * 4];
    #pragma unroll
    for (int a = 0; a < 4; ++a) {
      const float wv = Wks[j][ti * 4 + a];
      acc[a].x += wv * td4.x; acc[a].y += wv * td4.y;
      acc[a].z += wv * td4.z; acc[a].w += wv * td4.w;
    }
  }

  const float4* C4b = (const float4*)(C + (size_t)b * Hn * Hn);
  float4* out4 = (float4*)(out + (size_t)b * Hn * Hn);
  const float4 bv4 = *(const float4*)&bvs[tj4 * 4];
  const float4 tm4 = *(const float4*)&terms[tj4 * 4];
  const float4 c14 = *(const float4*)&c1s[tj4 * 4];
  #pragma unroll
  for (int a = 0; a < 4; ++a) {
    const int hh = ti * 4 + a;
    const int h = hs0 + hh;
    const float4 c = C4b[(size_t)h * 128 + d04 + tj4];
    const float ph = phs[hh], bkh = bks[hh], p2h = p2s[hh];
    float4 o;
    o.x = c.x + acc[a].x + ph * bv4.x + bkh * tm4.x - p2h * c14.x;
    o.y = c.y + acc[a].y + ph * bv4.y + bkh * tm4.y - p2h * c14.y;
    o.z = c.z + acc[a].z + ph * bv4.z + bkh * tm4.z - p2h * c14.z;
    o.w = c.w + acc[a].w + ph * bv4.w + bkh * tm4.w - p2h * c14.w;
    out4[(size_t)h * 128 + d04 + tj4] = o;
  }
}

// ---------------------------------------------------------------------------
extern "C" void kernel_launch(void* const* d_in, const int* in_sizes, int n_in,
                              void* d_out, int out_size, void* d_ws, size_t ws_size,
                              hipStream_t stream) {
  const float* hs = (const float*)d_in[0];
  const float* C  = (const float*)d_in[1];
  const float* Wk = (const float*)d_in[2];
  const float* bk = (const float*)d_in[3];
  const float* Wv = (const float*)d_in[4];
  const float* bv = (const float*)d_in[5];
  float* out = (float*)d_out;
  float* ws = (float*)d_ws;
  (void)in_sizes; (void)n_in; (void)out_size; (void)ws_size;

  hipLaunchKernelGGL(kA_pre,     dim3(321), dim3(256), 0, stream, Wk, bk, C, ws);
  hipLaunchKernelGGL(k1_stats,   dim3(512), dim3(256), 0, stream, hs, ws);
  hipLaunchKernelGGL(k1b_reduce, dim3(256), dim3(256), 0, stream, ws);
  hipLaunchKernelGGL(k2p_td,     dim3(128), dim3(256), 0, stream, Wk, Wv, ws);
  hipLaunchKernelGGL(k4_out,     dim3(512), dim3(256), 0, stream, C, Wk, bk, bv, ws, out);
}

// Round 9
// 61.215 us; speedup vs baseline: 1.5303x; 1.1467x over previous
//
#include <hip/hip_runtime.h>
#include <hip/hip_bf16.h>
#include <math.h>

namespace {
constexpr int Bn = 8;
constexpr int Ln = 8192;
constexpr int Rn = 64;
constexpr int Hn = 512;
constexpr int LT = 128;
constexpr int NSEG = Ln / LT;            // 64 segments per batch
constexpr int NK1 = Bn * NSEG;           // 512 k1 blocks
constexpr int NHC = 4;                   // M h-chunks (128 h each)

// workspace float offsets
constexpr size_t PS        = 8352;       // per-k1-block partial stride
constexpr size_t OFF_G     = 0;                                   // 64x64
constexpr size_t OFF_W     = 4096;                                // 64
constexpr size_t OFF_BB    = 4160;                                // 1 (+pad)
constexpr size_t OFF_STATS = 4224;                                // NK1 * PS
constexpr size_t OFF_A1R   = OFF_STATS + (size_t)NK1 * PS;        // B*4096
constexpr size_t OFF_A2R   = OFF_A1R + (size_t)Bn * 4096;         // B*4096
constexpr size_t OFF_U1R   = OFF_A2R + (size_t)Bn * 4096;         // B*64
constexpr size_t OFF_U2R   = OFF_U1R + (size_t)Bn * 64;           // B*64
constexpr size_t OFF_SIG   = OFF_U2R + (size_t)Bn * 64;           // B*2 (pad 64)
constexpr size_t OFF_MP    = OFF_SIG + 64;                        // B*NHC*64*H (M h-partials)
constexpr size_t OFF_C1P   = OFF_MP + (size_t)Bn * NHC * 64 * Hn; // B*NHC*H
constexpr size_t OFF_TD    = OFF_C1P + (size_t)Bn * NHC * Hn;     // B*64*H
constexpr size_t OFF_P1    = OFF_TD + (size_t)Bn * 64 * Hn;       // B*H
constexpr size_t OFF_P2    = OFF_P1 + (size_t)Bn * Hn;            // B*H
constexpr size_t OFF_Q1    = OFF_P2 + (size_t)Bn * Hn;            // B*H
constexpr size_t OFF_GV    = OFF_Q1 + (size_t)Bn * Hn;            // B*H     (g = u2^T M)
}

using short8v = __attribute__((ext_vector_type(8))) short;
using f32x4v  = __attribute__((ext_vector_type(4))) float;

// bf16 [64 r][128 l], 8-elem granules XOR-swizzled by row (validated R8)
__device__ __forceinline__ int bidx(int r, int l) {
  return (r << 7) + ((((l >> 3) ^ (r & 7)) << 3) | (l & 7));
}
// bf16 [128 l][64 r]
__device__ __forceinline__ int xlidx(int l, int r) {
  return (l << 6) + ((((r >> 3) ^ (l & 7)) << 3) | (r & 7));
}
// bf16 [64 i][64 k]
__device__ __forceinline__ int gbidx(int i, int k) {
  return (i << 6) + ((((k >> 3) ^ (i & 7)) << 3) | (k & 7));
}
__device__ __forceinline__ short tobf(float x) {
  __hip_bfloat16 h = __float2bfloat16(x);
  return __builtin_bit_cast(short, h);
}
__device__ __forceinline__ float frombf(short s) {
  union { unsigned int u; float f; } c;
  c.u = ((unsigned int)(unsigned short)s) << 16;
  return c.f;
}

// ---------------------------------------------------------------------------
// kA: blocks 0..63  : G[i][j] = Wk_i . Wk_j ; block 64: w = Wk*bk, bb = bk.bk
//     blocks 65..320: M h-partials, register-tiled (unchanged from R7/R8)
// grid 321 x 256
__global__ __launch_bounds__(256) void kA_pre(const float* __restrict__ Wk,
                                              const float* __restrict__ bk,
                                              const float* __restrict__ C,
                                              float* __restrict__ ws) {
  const int t = threadIdx.x;
  const int blk = blockIdx.x;

  if (blk < 64) {
    const int j = t >> 2, kq = t & 3;
    const float4* a4 = (const float4*)(Wk + (size_t)blk * Hn) + kq * 32;
    const float4* b4 = (const float4*)(Wk + (size_t)j * Hn) + kq * 32;
    float s0 = 0.f, s1 = 0.f, s2 = 0.f, s3 = 0.f;
    #pragma unroll 8
    for (int h = 0; h < 32; ++h) {
      const float4 x = a4[h], y = b4[h];
      s0 += x.x * y.x; s1 += x.y * y.y; s2 += x.z * y.z; s3 += x.w * y.w;
    }
    float s = (s0 + s1) + (s2 + s3);
    s += __shfl_down(s, 2, 4);
    s += __shfl_down(s, 1, 4);
    if (kq == 0) ws[OFF_G + blk * 64 + j] = s;
    return;
  }
  if (blk == 64) {
    const int i = t >> 2, kq = t & 3;
    const float4* a4 = (const float4*)(Wk + (size_t)i * Hn) + kq * 32;
    const float4* b4 = (const float4*)bk + kq * 32;
    float s0 = 0.f, s1 = 0.f, s2 = 0.f, s3 = 0.f;
    #pragma unroll 8
    for (int h = 0; h < 32; ++h) {
      const float4 x = a4[h], y = b4[h];
      s0 += x.x * y.x; s1 += x.y * y.y; s2 += x.z * y.z; s3 += x.w * y.w;
    }
    float s = (s0 + s1) + (s2 + s3);
    s += __shfl_down(s, 2, 4);
    s += __shfl_down(s, 1, 4);
    if (kq == 0) ws[OFF_W + i] = s;
    if (t < 4) {
      const float4* b4b = (const float4*)bk + t * 32;
      float q0 = 0.f, q1 = 0.f, q2 = 0.f, q3 = 0.f;
      #pragma unroll 8
      for (int h = 0; h < 32; ++h) {
        const float4 y = b4b[h];
        q0 += y.x * y.x; q1 += y.y * y.y; q2 += y.z * y.z; q3 += y.w * y.w;
      }
      float q = (q0 + q1) + (q2 + q3);
      q += __shfl_down(q, 2, 4);
      q += __shfl_down(q, 1, 4);
      if (t == 0) ws[OFF_BB] = q;
    }
    return;
  }

  // ---- M / c1 partials (register-tiled) ----
  __shared__ __align__(16) float WkS[64][132];
  __shared__ __align__(16) float Cs[128][68];
  __shared__ __align__(16) float bks[128];

  const int m = blk - 65;
  const int b = m >> 5;
  const int rem = m & 31;
  const int hc = rem >> 3;
  const int ds = rem & 7;
  const int h0 = hc * 128;
  const int d04 = ds * 16;

  const float4* Wk4 = (const float4*)Wk;
  const float4* C4b = (const float4*)(C + (size_t)b * Hn * Hn);
  #pragma unroll
  for (int p = 0; p < 8; ++p) {
    const int e = p * 256 + t;
    const int r = e >> 5, c4 = e & 31;
    *(float4*)&WkS[r][c4 * 4] = Wk4[(size_t)r * 128 + (h0 >> 2) + c4];
  }
  #pragma unroll
  for (int p = 0; p < 8; ++p) {
    const int e = p * 256 + t;
    const int r = e >> 4, c4 = e & 15;
    *(float4*)&Cs[r][c4 * 4] = C4b[(size_t)(h0 + r) * 128 + d04 + c4];
  }
  if (t < 32) *(float4*)&bks[t * 4] = ((const float4*)&bk[h0])[t];
  __syncthreads();

  const int ig = t >> 4;
  const int i4 = ig * 4;
  const int d4 = t & 15;
  float4 acc0 = make_float4(0.f, 0.f, 0.f, 0.f);
  float4 acc1 = make_float4(0.f, 0.f, 0.f, 0.f);
  float4 acc2 = make_float4(0.f, 0.f, 0.f, 0.f);
  float4 acc3 = make_float4(0.f, 0.f, 0.f, 0.f);
  float4 c1a  = make_float4(0.f, 0.f, 0.f, 0.f);

  #pragma unroll 4
  for (int h4 = 0; h4 < 128; h4 += 4) {
    const float4 w0 = *(const float4*)&WkS[i4 + 0][h4];
    const float4 w1 = *(const float4*)&WkS[i4 + 1][h4];
    const float4 w2 = *(const float4*)&WkS[i4 + 2][h4];
    const float4 w3 = *(const float4*)&WkS[i4 + 3][h4];
    const float4 c0 = *(const float4*)&Cs[h4 + 0][d4 * 4];
    const float4 c1 = *(const float4*)&Cs[h4 + 1][d4 * 4];
    const float4 c2 = *(const float4*)&Cs[h4 + 2][d4 * 4];
    const float4 c3 = *(const float4*)&Cs[h4 + 3][d4 * 4];

    acc0.x += w0.x*c0.x + w0.y*c1.x + w0.z*c2.x + w0.w*c3.x;
    acc0.y += w0.x*c0.y + w0.y*c1.y + w0.z*c2.y + w0.w*c3.y;
    acc0.z += w0.x*c0.z + w0.y*c1.z + w0.z*c2.z + w0.w*c3.z;
    acc0.w += w0.x*c0.w + w0.y*c1.w + w0.z*c2.w + w0.w*c3.w;
    acc1.x += w1.x*c0.x + w1.y*c1.x + w1.z*c2.x + w1.w*c3.x;
    acc1.y += w1.x*c0.y + w1.y*c1.y + w1.z*c2.y + w1.w*c3.y;
    acc1.z += w1.x*c0.z + w1.y*c1.z + w1.z*c2.z + w1.w*c3.z;
    acc1.w += w1.x*c0.w + w1.y*c1.w + w1.z*c2.w + w1.w*c3.w;
    acc2.x += w2.x*c0.x + w2.y*c1.x + w2.z*c2.x + w2.w*c3.x;
    acc2.y += w2.x*c0.y + w2.y*c1.y + w2.z*c2.y + w2.w*c3.y;
    acc2.z += w2.x*c0.z + w2.y*c1.z + w2.z*c2.z + w2.w*c3.z;
    acc2.w += w2.x*c0.w + w2.y*c1.w + w2.z*c2.w + w2.w*c3.w;
    acc3.x += w3.x*c0.x + w3.y*c1.x + w3.z*c2.x + w3.w*c3.x;
    acc3.y += w3.x*c0.y + w3.y*c1.y + w3.z*c2.y + w3.w*c3.y;
    acc3.z += w3.x*c0.z + w3.y*c1.z + w3.z*c2.z + w3.w*c3.z;
    acc3.w += w3.x*c0.w + w3.y*c1.w + w3.z*c2.w + w3.w*c3.w;

    if (ig == 0) {
      const float b0 = bks[h4 + 0], b1 = bks[h4 + 1];
      const float b2 = bks[h4 + 2], b3 = bks[h4 + 3];
      c1a.x += b0*c0.x + b1*c1.x + b2*c2.x + b3*c3.x;
      c1a.y += b0*c0.y + b1*c1.y + b2*c2.y + b3*c3.y;
      c1a.z += b0*c0.z + b1*c1.z + b2*c2.z + b3*c3.z;
      c1a.w += b0*c0.w + b1*c1.w + b2*c2.w + b3*c3.w;
    }
  }

  float4* MP4 = (float4*)(ws + OFF_MP);
  const size_t base = (size_t)(b * NHC + hc) * 64;
  MP4[(base + i4 + 0) * 128 + d04 + d4] = acc0;
  MP4[(base + i4 + 1) * 128 + d04 + d4] = acc1;
  MP4[(base + i4 + 2) * 128 + d04 + d4] = acc2;
  MP4[(base + i4 + 3) * 128 + d04 + d4] = acc3;
  if (ig == 0) {
    float4* c14 = (float4*)(ws + OFF_C1P);
    c14[(size_t)(b * NHC + hc) * 128 + d04 + d4] = c1a;
  }
}

// ---------------------------------------------------------------------------
// k1: per 128-row tile, fully on the matrix pipe.
//   stage X as bf16 twice (XB=[r][l], XL=[l][r]) + G as bf16.
//   T = G@X via MFMA -> n2 epilogue in-register -> d1s.
//   A1 = E^T X, A2 = E^T E via MFMA with E = diag(d)X built on the fly.
// LDS ~43KB -> 3 blocks/CU. grid 512 x 256
__global__ __launch_bounds__(256, 3) void k1_stats(const float* __restrict__ hs,
                                                   float* __restrict__ ws) {
  __shared__ __align__(16) short XB[8192];   // bf16 X^T [r=64][l=128], swizzled
  __shared__ __align__(16) short XL[8192];   // bf16 X   [l=128][r=64], swizzled
  __shared__ __align__(16) short Gb[4096];   // bf16 G   [i=64][k=64], swizzled
  __shared__ __align__(16) float n2p[4][128];
  __shared__ __align__(16) float d1s[LT];
  __shared__ __align__(16) float wsh[64];

  const int t = threadIdx.x;
  const int idx = blockIdx.x;
  const int b = idx >> 6;
  const int seg = idx & 63;

  if (t < 64) wsh[t] = ws[OFF_W + t];
  const float bb = ws[OFF_BB];

  // stage G -> bf16 swizzled
  {
    const float4* G4 = (const float4*)(ws + OFF_G);
    #pragma unroll
    for (int p = 0; p < 4; ++p) {
      const int e = p * 256 + t;
      const float4 g = G4[e];
      const int i = e >> 4, k0 = (e & 15) << 2;
      short4 gp;
      gp.x = tobf(g.x); gp.y = tobf(g.y); gp.z = tobf(g.z); gp.w = tobf(g.w);
      *(short4*)&Gb[gbidx(i, k0)] = gp;
    }
  }
  // stage X -> XB (transposed) + XL, bf16 swizzled
  {
    const float4* src = (const float4*)(hs + ((size_t)b * Ln + (size_t)seg * LT) * Rn);
    #pragma unroll
    for (int k = 0; k < 8; ++k) {
      const int f = k * 256 + t;
      const float4 v = src[f];
      const int l = f >> 4, j0 = (f & 15) << 2;
      const short s0 = tobf(v.x), s1 = tobf(v.y), s2 = tobf(v.z), s3 = tobf(v.w);
      XB[bidx(j0 + 0, l)] = s0;
      XB[bidx(j0 + 1, l)] = s1;
      XB[bidx(j0 + 2, l)] = s2;
      XB[bidx(j0 + 3, l)] = s3;
      short4 xp; xp.x = s0; xp.y = s1; xp.z = s2; xp.w = s3;
      *(short4*)&XL[xlidx(l, j0)] = xp;
    }
  }
  __syncthreads();

  const int lane = t & 63;
  const int w = t >> 6;              // wave -> i-strip [16w, 16w+16)
  const int lo = lane & 15;
  const int hi = lane >> 4;

  // T = G @ X (64x128, K=64) via MFMA; per-jt n2 partial
  {
    short8v ga[2];
    #pragma unroll
    for (int kc = 0; kc < 2; ++kc)
      ga[kc] = *(const short8v*)&Gb[gbidx(w * 16 + lo, kc * 32 + hi * 8)];
    #pragma unroll
    for (int jt = 0; jt < 8; ++jt) {
      f32x4v acc = {0.f, 0.f, 0.f, 0.f};
      #pragma unroll
      for (int kc = 0; kc < 2; ++kc) {
        const short8v xb = *(const short8v*)&XL[xlidx(jt * 16 + lo, kc * 32 + hi * 8)];
        acc = __builtin_amdgcn_mfma_f32_16x16x32_bf16(ga[kc], xb, acc, 0, 0, 0);
      }
      float p = 0.f;
      #pragma unroll
      for (int reg = 0; reg < 4; ++reg) {
        const int i = w * 16 + hi * 4 + reg;
        p += frombf(XB[bidx(i, jt * 16 + lo)]) * (acc[reg] + 2.0f * wsh[i]);
      }
      p += __shfl_xor(p, 16, 64);
      p += __shfl_xor(p, 32, 64);
      if (hi == 0) n2p[w][jt * 16 + lo] = p;
    }
  }
  __syncthreads();
  if (t < LT) {
    const float n2 = fmaxf(bb + ((n2p[0][t] + n2p[1][t]) + (n2p[2][t] + n2p[3][t])), 0.0f);
    d1s[t] = 1.0f / fmaxf(sqrtf(n2), 1e-12f);
  }
  __syncthreads();

  float* P = ws + OFF_STATS + (size_t)idx * PS;

  float sg1 = 0.f, sg2 = 0.f;
  if (t < 64) {
    const float da = d1s[t], db = d1s[t + 64];
    float a1 = da + db;
    float a2 = da * da + db * db;
    #pragma unroll
    for (int off = 32; off > 0; off >>= 1) {
      a1 += __shfl_down(a1, off, 64);
      a2 += __shfl_down(a2, off, 64);
    }
    sg1 = a1; sg2 = a2;
  }

  // u1/u2 partials (fp32, from XB + d1s)
  {
    const int r = t >> 2;
    const int lq = (t & 3) * 32;
    float u1p = 0.f, u2p = 0.f;
    #pragma unroll
    for (int g = 0; g < 4; ++g) {
      const int l0 = lq + g * 8;
      const short8v xv = *(const short8v*)&XB[bidx(r, l0)];
      #pragma unroll
      for (int e = 0; e < 8; ++e) {
        const float d = d1s[l0 + e];
        const float x = frombf(xv[e]);
        u1p += d * x;
        u2p += d * d * x;
      }
    }
    u1p += __shfl_down(u1p, 2, 4); u1p += __shfl_down(u1p, 1, 4);
    u2p += __shfl_down(u2p, 2, 4); u2p += __shfl_down(u2p, 1, 4);
    if ((t & 3) == 0) {
      P[8192 + r] = u1p;
      P[8256 + r] = u2p;
    }
  }

  // A1 = E^T X (P+0), A2 = E^T E (P+4096); E = diag(d) X on the fly. K=128.
  {
    short8v xa[4], ea[4];
    #pragma unroll
    for (int kc = 0; kc < 4; ++kc) {
      xa[kc] = *(const short8v*)&XB[bidx(w * 16 + lo, kc * 32 + hi * 8)];
      #pragma unroll
      for (int e = 0; e < 8; ++e)
        ea[kc][e] = tobf(d1s[kc * 32 + hi * 8 + e] * frombf(xa[kc][e]));
    }
    #pragma unroll
    for (int jt = 0; jt < 4; ++jt) {
      f32x4v a1 = {0.f, 0.f, 0.f, 0.f};
      f32x4v a2 = {0.f, 0.f, 0.f, 0.f};
      #pragma unroll
      for (int kc = 0; kc < 4; ++kc) {
        const short8v xb = *(const short8v*)&XB[bidx(jt * 16 + lo, kc * 32 + hi * 8)];
        short8v eb;
        #pragma unroll
        for (int e = 0; e < 8; ++e)
          eb[e] = tobf(d1s[kc * 32 + hi * 8 + e] * frombf(xb[e]));
        a1 = __builtin_amdgcn_mfma_f32_16x16x32_bf16(ea[kc], xb, a1, 0, 0, 0);
        a2 = __builtin_amdgcn_mfma_f32_16x16x32_bf16(ea[kc], eb, a2, 0, 0, 0);
      }
      #pragma unroll
      for (int reg = 0; reg < 4; ++reg) {
        P[(w * 16 + hi * 4 + reg) * 64 + jt * 16 + lo] = a1[reg];
        P[4096 + (w * 16 + hi * 4 + reg) * 64 + jt * 16 + lo] = a2[reg];
      }
    }
  }

  if (t == 0) { P[8320] = sg1; P[8321] = sg2; }
}

// ---------------------------------------------------------------------------
// k1b: reduce 64 partials per batch -> A1R, A2R, U1R, U2R, SIG
// grid 256 (= b(8) x sel(2) x q(16)) x 256
__global__ __launch_bounds__(256) void k1b_reduce(float* __restrict__ ws) {
  const int t = threadIdx.x;
  const int blk = blockIdx.x;
  const int b = blk >> 5, sel = (blk >> 4) & 1, q = blk & 15;
  const float* SB = ws + OFF_STATS + (size_t)b * 64 * PS + (size_t)sel * 4096;
  float* dst = ws + (sel ? OFF_A2R : OFF_A1R) + (size_t)b * 4096;
  const int e = q * 256 + t;
  float s = 0.f;
  #pragma unroll 8
  for (int p = 0; p < 64; ++p) s += SB[(size_t)p * PS + e];
  dst[e] = s;
  if (sel == 0 && q == 0) {
    const float* UB = ws + OFF_STATS + (size_t)b * 64 * PS;
    if (t < 64) {
      float s2 = 0.f;
      #pragma unroll 8
      for (int p = 0; p < 64; ++p) s2 += UB[(size_t)p * PS + 8192 + t];
      ws[OFF_U1R + b * 64 + t] = s2;
    } else if (t < 128) {
      const int i = t - 64;
      float s2 = 0.f;
      #pragma unroll 8
      for (int p = 0; p < 64; ++p) s2 += UB[(size_t)p * PS + 8256 + i];
      ws[OFF_U2R + b * 64 + i] = s2;
    } else if (t == 128) {
      float s1 = 0.f, s2 = 0.f;
      for (int p = 0; p < 64; ++p) {
        s1 += UB[(size_t)p * PS + 8320];
        s2 += UB[(size_t)p * PS + 8321];
      }
      ws[OFF_SIG + b * 2] = s1;
      ws[OFF_SIG + b * 2 + 1] = s2;
    }
  }
}

// ---------------------------------------------------------------------------
// k2p: Td = A1 @ Wv - A2 @ M  (M = sum of 4 h-partials)
//      p1 = Wk^T u1, p2 = Wk^T u2, q1 = Wv^T u1, g = u2^T M
// grid 128 (= b(8) x ds(16, 32-wide)) x 256
__global__ __launch_bounds__(256) void k2p_td(const float* __restrict__ Wk,
                                              const float* __restrict__ Wv,
                                              float* __restrict__ ws) {
  __shared__ __align__(16) float A1s[64][66];
  __shared__ __align__(16) float A2s[64][66];
  __shared__ __align__(16) float Wvt[64][36];
  __shared__ __align__(16) float Mt[64][36];
  __shared__ __align__(16) float u1s[64];
  __shared__ __align__(16) float u2s[64];

  const int t = threadIdx.x;
  const int blk = blockIdx.x;
  const int b = blk >> 4;
  const int ds = blk & 15;
  const int d04 = ds * 8;

  const float4* A1R4 = (const float4*)(ws + OFF_A1R + (size_t)b * 4096);
  const float4* A2R4 = (const float4*)(ws + OFF_A2R + (size_t)b * 4096);
  #pragma unroll
  for (int p = 0; p < 4; ++p) {
    const int idx = p * 256 + t;
    const int r = idx >> 4, c0 = (idx & 15) * 4;
    *(float4*)&A1s[r][c0] = A1R4[idx];
    *(float4*)&A2s[r][c0] = A2R4[idx];
  }
  const float4* Wv4 = (const float4*)Wv;
  const float4* MP4 = (const float4*)(ws + OFF_MP);
  #pragma unroll
  for (int p = 0; p < 2; ++p) {
    const int idx = p * 256 + t;
    const int r = idx >> 3, c4 = idx & 7;
    *(float4*)&Wvt[r][c4 * 4] = Wv4[(size_t)r * 128 + d04 + c4];
    float4 m = MP4[((size_t)(b * NHC + 0) * 64 + r) * 128 + d04 + c4];
    #pragma unroll
    for (int q = 1; q < NHC; ++q) {
      const float4 mq = MP4[((size_t)(b * NHC + q) * 64 + r) * 128 + d04 + c4];
      m.x += mq.x; m.y += mq.y; m.z += mq.z; m.w += mq.w;
    }
    *(float4*)&Mt[r][c4 * 4] = m;
  }
  if (t < 16) {
    *(float4*)&u1s[t * 4] = *(const float4*)(ws + OFF_U1R + b * 64 + t * 4);
  } else if (t < 32) {
    const int i = t - 16;
    *(float4*)&u2s[i * 4] = *(const float4*)(ws + OFF_U2R + b * 64 + i * 4);
  }
  __syncthreads();

  const int ig = t >> 3;
  const int tj4 = t & 7;
  float4 acc0 = make_float4(0.f, 0.f, 0.f, 0.f);
  float4 acc1 = make_float4(0.f, 0.f, 0.f, 0.f);
  #pragma unroll 8
  for (int j = 0; j < 64; ++j) {
    const float4 wv = *(const float4*)&Wvt[j][tj4 * 4];
    const float4 mv = *(const float4*)&Mt[j][tj4 * 4];
    const float a10 = A1s[ig * 2][j], a20 = A2s[ig * 2][j];
    const float a11 = A1s[ig * 2 + 1][j], a21 = A2s[ig * 2 + 1][j];
    acc0.x += a10 * wv.x - a20 * mv.x; acc0.y += a10 * wv.y - a20 * mv.y;
    acc0.z += a10 * wv.z - a20 * mv.z; acc0.w += a10 * wv.w - a20 * mv.w;
    acc1.x += a11 * wv.x - a21 * mv.x; acc1.y += a11 * wv.y - a21 * mv.y;
    acc1.z += a11 * wv.z - a21 * mv.z; acc1.w += a11 * wv.w - a21 * mv.w;
  }
  float4* Td4 = (float4*)(ws + OFF_TD + (size_t)b * 64 * Hn);
  Td4[(size_t)(ig * 2)     * 128 + d04 + tj4] = acc0;
  Td4[(size_t)(ig * 2 + 1) * 128 + d04 + tj4] = acc1;

  if (t < 32) {
    const int d = ds * 32 + t;
    float q1 = 0.f, g = 0.f;
    #pragma unroll 8
    for (int i = 0; i < 64; ++i) {
      q1 += u1s[i] * Wvt[i][t];
      g  += u2s[i] * Mt[i][t];
    }
    ws[OFF_Q1 + (size_t)b * Hn + d] = q1;
    ws[OFF_GV + (size_t)b * Hn + d] = g;
  } else if (t < 64) {
    const int h = ds * 32 + (t - 32);
    float p1 = 0.f, p2 = 0.f;
    #pragma unroll 8
    for (int i = 0; i < 64; ++i) {
      const float wv = Wk[(size_t)i * Hn + h];
      p1 += wv * u1s[i];
      p2 += wv * u2s[i];
    }
    ws[OFF_P1 + (size_t)b * Hn + h] = p1;
    ws[OFF_P2 + (size_t)b * Hn + h] = p2;
  }
}

// ---------------------------------------------------------------------------
// k4: out = C + Wk^T Td + (p1 + sig1*bk) (x) bv + bk (x) (q1 - g - sig2*c1) - p2 (x) c1
// grid 512 (= b(8) x hstrip(8, 64-wide) x dstrip(8, 64-wide)) x 256
__global__ __launch_bounds__(256) void k4_out(const float* __restrict__ C,
                                              const float* __restrict__ Wk,
                                              const float* __restrict__ bk,
                                              const float* __restrict__ bv,
                                              const float* __restrict__ ws,
                                              float* __restrict__ out) {
  __shared__ __align__(16) float Tds[64][68];
  __shared__ __align__(16) float Wks[64][68];
  __shared__ float phs[64], bks[64], p2s[64];
  __shared__ float bvs[64], terms[64], c1s[64];

  const int t = threadIdx.x;
  const int blk = blockIdx.x;
  const int b = blk >> 6;
  const int rem = blk & 63;
  const int hs0 = (rem >> 3) * 64;
  const int d04 = (rem & 7) * 16;
  const float sg1 = ws[OFF_SIG + b * 2];
  const float sg2 = ws[OFF_SIG + b * 2 + 1];

  const float4* TdG4 = (const float4*)(ws + OFF_TD + (size_t)b * 64 * Hn);
  const float4* Wk4 = (const float4*)Wk;
  #pragma unroll
  for (int p = 0; p < 4; ++p) {
    const int e = p * 256 + t;
    const int r = e >> 4, c4 = e & 15;
    *(float4*)&Tds[r][c4 * 4] = TdG4[(size_t)r * 128 + d04 + c4];
    *(float4*)&Wks[r][c4 * 4] = Wk4[(size_t)r * 128 + (hs0 >> 2) + c4];
  }
  if (t < 64) {
    const int h = hs0 + t;
    const float bkv = bk[h];
    bks[t] = bkv;
    phs[t] = ws[OFF_P1 + (size_t)b * Hn + h] + sg1 * bkv;
    p2s[t] = ws[OFF_P2 + (size_t)b * Hn + h];
  } else if (t < 128) {
    const int dd = t - 64;
    const int d = d04 * 4 + dd;
    float c1 = 0.f;
    #pragma unroll
    for (int q = 0; q < NHC; ++q)
      c1 += ws[OFF_C1P + (size_t)(b * NHC + q) * Hn + d];
    c1s[dd] = c1;
    bvs[dd] = bv[d];
    terms[dd] = ws[OFF_Q1 + (size_t)b * Hn + d] - ws[OFF_GV + (size_t)b * Hn + d] - sg2 * c1;
  }
  __syncthreads();

  const int ti = t >> 4;
  const int tj4 = t & 15;
  float4 acc[4];
  #pragma unroll
  for (int a = 0; a < 4; ++a) acc[a] = make_float4(0.f, 0.f, 0.f, 0.f);
  for (int j = 0; j < 64; ++j) {
    const float4 td4 = *(const float4*)&Tds[j][tj4 * 4];
    #pragma unroll
    for (int a = 0; a < 4; ++a) {
      const float wv = Wks[j][ti * 4 + a];
      acc[a].x += wv * td4.x; acc[a].y += wv * td4.y;
      acc[a].z += wv * td4.z; acc[a].w += wv * td4.w;
    }
  }

  const float4* C4b = (const float4*)(C + (size_t)b * Hn * Hn);
  float4* out4 = (float4*)(out + (size_t)b * Hn * Hn);
  const float4 bv4 = *(const float4*)&bvs[tj4 * 4];
  const float4 tm4 = *(const float4*)&terms[tj4 * 4];
  const float4 c14 = *(const float4*)&c1s[tj4 * 4];
  #pragma unroll
  for (int a = 0; a < 4; ++a) {
    const int hh = ti * 4 + a;
    const int h = hs0 + hh;
    const float4 c = C4b[(size_t)h * 128 + d04 + tj4];
    const float ph = phs[hh], bkh = bks[hh], p2h = p2s[hh];
    float4 o;
    o.x = c.x + acc[a].x + ph * bv4.x + bkh * tm4.x - p2h * c14.x;
    o.y = c.y + acc[a].y + ph * bv4.y + bkh * tm4.y - p2h * c14.y;
    o.z = c.z + acc[a].z + ph * bv4.z + bkh * tm4.z - p2h * c14.z;
    o.w = c.w + acc[a].w + ph * bv4.w + bkh * tm4.w - p2h * c14.w;
    out4[(size_t)h * 128 + d04 + tj4] = o;
  }
}

// ---------------------------------------------------------------------------
extern "C" void kernel_launch(void* const* d_in, const int* in_sizes, int n_in,
                              void* d_out, int out_size, void* d_ws, size_t ws_size,
                              hipStream_t stream) {
  const float* hs = (const float*)d_in[0];
  const float* C  = (const float*)d_in[1];
  const float* Wk = (const float*)d_in[2];
  const float* bk = (const float*)d_in[3];
  const float* Wv = (const float*)d_in[4];
  const float* bv = (const float*)d_in[5];
  float* out = (float*)d_out;
  float* ws = (float*)d_ws;
  (void)in_sizes; (void)n_in; (void)out_size; (void)ws_size;

  hipLaunchKernelGGL(kA_pre,     dim3(321), dim3(256), 0, stream, Wk, bk, C, ws);
  hipLaunchKernelGGL(k1_stats,   dim3(512), dim3(256), 0, stream, hs, ws);
  hipLaunchKernelGGL(k1b_reduce, dim3(256), dim3(256), 0, stream, ws);
  hipLaunchKernelGGL(k2p_td,     dim3(128), dim3(256), 0, stream, Wk, Wv, ws);
  hipLaunchKernelGGL(k4_out,     dim3(512), dim3(256), 0, stream, C, Wk, bk, bv, ws, out);
}